// Round 16
// baseline (52.630 us; speedup 1.0000x reference)
//
#include <hip/hip_runtime.h>

// PillarFeatureNet fused, 3 kernels, single feature read, 256-thr blocks:
//  K1 pfn_main: wave per pillar (run of ~3): stage to LDS; per-lane raw
//     second moments packed f32x2 (6 inst/point); pure-DPP reductions +
//     readlane(63) (zero DS ops) -> rec[k] + lane-parallel cross-moments
//     (single oacc reg); channel-PAIR sign(gamma)-folded MAX extrema with
//     packed v_pk_fma/v_pk_max (10 inst/point, 1 ds_read_b128 = 4 pts).
//     Block partials -> uniform p54[54][NBLK].
//  K2 pfn_finalize (512 thr): reduce p54 rows, assemble 54 augmented
//     moments (verified index maps), per-channel scale/shift -> ss.
//  K3 pfn_apply: bias from rec, un-fold by sign(scale), mask clamp, BN+relu.
// p54 rows: [0..3]=Q1 [4..13]=Q2 [14..33]=S [34..38]=U1 [39..53]=U2
// features [K,P,4] f32, num_voxels [K] i32, coors [K,4] i32,
// W [9,64] f32, gamma/beta [64] f32 -> out [K,64] f32.

typedef float f32x2 __attribute__((ext_vector_type(2)));

#define NBLK 2048  // K1 blocks (divisible by 4)

// Pure-DPP wave sum; lane 63 holds the wave total. Zero DS ops.
__device__ __forceinline__ float wred63(float v) {
  int t;
  t = __builtin_amdgcn_update_dpp(0, __float_as_int(v), 0xB1, 0xf, 0xf, true);
  v += __int_as_float(t);  // quad_perm xor1
  t = __builtin_amdgcn_update_dpp(0, __float_as_int(v), 0x4E, 0xf, 0xf, true);
  v += __int_as_float(t);  // quad_perm xor2
  t = __builtin_amdgcn_update_dpp(0, __float_as_int(v), 0x141, 0xf, 0xf, true);
  v += __int_as_float(t);  // row_half_mirror = xor7
  t = __builtin_amdgcn_update_dpp(0, __float_as_int(v), 0x140, 0xf, 0xf, true);
  v += __int_as_float(t);  // row_mirror = xor15 -> row sums
  t = __builtin_amdgcn_update_dpp(0, __float_as_int(v), 0x142, 0xa, 0xf, true);
  v += __int_as_float(t);  // row_bcast15 -> rows 1,3
  t = __builtin_amdgcn_update_dpp(0, __float_as_int(v), 0x143, 0xc, 0xf, true);
  v += __int_as_float(t);  // row_bcast31 -> rows 2,3 (lane63 total)
  return v;
}
__device__ __forceinline__ float wsum_bcast(float v) {
  return __int_as_float(
      __builtin_amdgcn_readlane(__float_as_int(wred63(v)), 63));
}

// ---------------- K1 ----------------
__global__ void __launch_bounds__(256, 6) pfn_main(
    const float4* __restrict__ feat, const int* __restrict__ nvox,
    const int* __restrict__ coors, int K, int P, int cnt,
    const float* __restrict__ W, const float* __restrict__ gamma,
    float* __restrict__ p54, float4* __restrict__ ext,
    float4* __restrict__ rec) {
  __shared__ float4 pts[4][108];
  __shared__ float red[4][56];
  const int lane = threadIdx.x & 63;
  const int wid = threadIdx.x >> 6;
  const int q = lane & 15;  // channel quad (channels 4q..4q+3)
  const int g = lane >> 4;  // point group 0..3

  // ---- moment-row decode for this lane (constant) ----
  int sa = 0, sb = 0, ub = 0, ub2 = 0;
  if (lane >= 14 && lane < 34) { sa = (lane - 14) / 5; sb = (lane - 14) % 5; }
  if (lane >= 39 && lane < 54) {
    int r2 = lane - 39, b = 0;
    while (r2 >= 5 - b) { r2 -= 5 - b; ++b; }
    ub = b; ub2 = b + r2;
  }

  // ---- sign(gamma)-folded weight channel-pairs (packed f32x2) ----
  const f32x2* W2 = (const f32x2*)W;  // [9][32] channel pairs
  const int ja = 2 * q, jb = 2 * q + 1;  // pairs (4q,4q+1), (4q+2,4q+3)
  const f32x2 ga = ((const f32x2*)gamma)[ja];
  const f32x2 gb = ((const f32x2*)gamma)[jb];
  f32x2 sga, sgb;
  sga.x = (ga.x >= 0.f) ? 1.f : -1.f; sga.y = (ga.y >= 0.f) ? 1.f : -1.f;
  sgb.x = (gb.x >= 0.f) ? 1.f : -1.f; sgb.y = (gb.y >= 0.f) ? 1.f : -1.f;
  const f32x2 wx01 = (W2[0 * 32 + ja] + W2[4 * 32 + ja] + W2[7 * 32 + ja]) * sga;
  const f32x2 wx23 = (W2[0 * 32 + jb] + W2[4 * 32 + jb] + W2[7 * 32 + jb]) * sgb;
  const f32x2 wy01 = (W2[1 * 32 + ja] + W2[5 * 32 + ja] + W2[8 * 32 + ja]) * sga;
  const f32x2 wy23 = (W2[1 * 32 + jb] + W2[5 * 32 + jb] + W2[8 * 32 + jb]) * sgb;
  const f32x2 wz01 = (W2[2 * 32 + ja] + W2[6 * 32 + ja]) * sga;
  const f32x2 wz23 = (W2[2 * 32 + jb] + W2[6 * 32 + jb]) * sgb;
  const f32x2 w301 = W2[3 * 32 + ja] * sga;
  const f32x2 w323 = W2[3 * 32 + jb] * sgb;

  // packed raw second moments: pA=(xx,yy) pB=(xz,yw) pC=(xw,yz) pD=(zz,ww)
  f32x2 pA = {0, 0}, pB = {0, 0}, pC = {0, 0}, pD = {0, 0};
  float e0 = 0.f, e1 = 0.f;  // xy, zw
  float oacc = 0.f;

  const int gw = blockIdx.x * 4 + wid;
  const int k0 = gw * cnt;
  const int kend = (k0 + cnt < K) ? k0 + cnt : K;
  const bool hih = lane < (P - 64);  // P in (64,128]

  for (int k = k0; k < kend; ++k) {
    const size_t base = (size_t)k * P;
    const float4 f0 = feat[base + lane];
    float4 f1;
    if (hih) f1 = feat[base + 64 + lane];
    const int nv = nvox[k];

    // stage (single buffer; wave-private row, same-wave ordering safe)
    pts[wid][lane] = f0;
    if (hih) pts[wid][64 + lane] = f1;

    // per-lane sums + packed raw second moments
    float sax = f0.x, say = f0.y, saz = f0.z;
    float svx = 0, svy = 0, svz = 0, svw = 0;
    if (lane < nv) {
      svx = f0.x; svy = f0.y; svz = f0.z; svw = f0.w;
      const f32x2 f01 = {f0.x, f0.y}, f23 = {f0.z, f0.w};
      const f32x2 f32r = {f0.w, f0.z};
      pA += f01 * f01; pB += f01 * f23; pC += f01 * f32r; pD += f23 * f23;
      e0 = fmaf(f0.x, f0.y, e0); e1 = fmaf(f0.z, f0.w, e1);
    }
    if (hih) {
      sax += f1.x; say += f1.y; saz += f1.z;
      if (64 + lane < nv) {
        svx += f1.x; svy += f1.y; svz += f1.z; svw += f1.w;
        const f32x2 f01 = {f1.x, f1.y}, f23 = {f1.z, f1.w};
        const f32x2 f32r = {f1.w, f1.z};
        pA += f01 * f01; pB += f01 * f23; pC += f01 * f32r; pD += f23 * f23;
        e0 = fmaf(f1.x, f1.y, e0); e1 = fmaf(f1.z, f1.w, e1);
      }
    }

    // 7 pure-DPP reductions -> uniform wave totals (zero DS ops)
    const float rx = wsum_bcast(sax);
    const float ry = wsum_bcast(say);
    const float rz = wsum_bcast(saz);
    const float vx = wsum_bcast(svx);
    const float vy = wsum_bcast(svy);
    const float vz = wsum_bcast(svz);
    const float vw = wsum_bcast(svw);

    const float nvf = (float)nv, inv = 1.f / nvf;
    const float cx = (float)coors[k * 4 + 3] * 0.2f + 0.1f;
    const float cy = (float)coors[k * 4 + 2] * 0.2f - 39.9f;
    const float o0 = -rx * inv, o1 = -ry * inv, o2 = -rz * inv;
    const float o3 = -cx, o4 = -cy;

    // lane-parallel cross-moment accumulation (1 register)
    {
      float add = 0.f;
      if (lane < 4) {
        add = (lane == 0) ? vx : (lane == 1) ? vy : (lane == 2) ? vz : vw;
      } else if (lane >= 14 && lane < 34) {
        const float sva = (sa == 0) ? vx : (sa == 1) ? vy : (sa == 2) ? vz : vw;
        const float ob = (sb == 0) ? o0 : (sb == 1) ? o1
                       : (sb == 2) ? o2 : (sb == 3) ? o3 : o4;
        add = sva * ob;
      } else if (lane >= 34 && lane < 39) {
        const int b = lane - 34;
        const float ob = (b == 0) ? o0 : (b == 1) ? o1
                       : (b == 2) ? o2 : (b == 3) ? o3 : o4;
        add = nvf * ob;
      } else if (lane >= 39 && lane < 54) {
        const float oa = (ub == 0) ? o0 : (ub == 1) ? o1
                       : (ub == 2) ? o2 : (ub == 3) ? o3 : o4;
        const float ob = (ub2 == 0) ? o0 : (ub2 == 1) ? o1
                       : (ub2 == 2) ? o2 : (ub2 == 3) ? o3 : o4;
        add = nvf * oa * ob;
      }
      oacc += add;
    }

    if (lane == 0) {
      float4 r0; r0.x = vx; r0.y = vy; r0.z = vz; r0.w = vw;
      float4 r1; r1.x = rx; r1.y = ry; r1.z = rz; r1.w = nvf;
      rec[2 * (size_t)k] = r0;
      rec[2 * (size_t)k + 1] = r1;
    }

    // channel-pair packed MAX extrema (v_pk_fma / v_pk_max)
    f32x2 m01 = {-3e38f, -3e38f}, m23 = {-3e38f, -3e38f};
    int p = 0;
    for (; p + 8 <= nv; p += 8) {
      const float4 fa = pts[wid][p + g];
      const float4 fb = pts[wid][p + 4 + g];
      f32x2 ba01 = wx01 * fa.x + wy01 * fa.y + wz01 * fa.z + w301 * fa.w;
      f32x2 ba23 = wx23 * fa.x + wy23 * fa.y + wz23 * fa.z + w323 * fa.w;
      f32x2 bb01 = wx01 * fb.x + wy01 * fb.y + wz01 * fb.z + w301 * fb.w;
      f32x2 bb23 = wx23 * fb.x + wy23 * fb.y + wz23 * fb.z + w323 * fb.w;
      m01 = __builtin_elementwise_max(m01, ba01);
      m23 = __builtin_elementwise_max(m23, ba23);
      m01 = __builtin_elementwise_max(m01, bb01);
      m23 = __builtin_elementwise_max(m23, bb23);
    }
    if (p < nv) {  // predicated tail octet
      const int i0 = p + g, i1 = p + 4 + g;
      const float4 fa = pts[wid][i0];
      const float4 fb = pts[wid][i1];
      if (i0 < nv) {
        f32x2 ba01 = wx01 * fa.x + wy01 * fa.y + wz01 * fa.z + w301 * fa.w;
        f32x2 ba23 = wx23 * fa.x + wy23 * fa.y + wz23 * fa.z + w323 * fa.w;
        m01 = __builtin_elementwise_max(m01, ba01);
        m23 = __builtin_elementwise_max(m23, ba23);
      }
      if (i1 < nv) {
        f32x2 bb01 = wx01 * fb.x + wy01 * fb.y + wz01 * fb.z + w301 * fb.w;
        f32x2 bb23 = wx23 * fb.x + wy23 * fb.y + wz23 * fb.z + w323 * fb.w;
        m01 = __builtin_elementwise_max(m01, bb01);
        m23 = __builtin_elementwise_max(m23, bb23);
      }
    }
    float4 m4; m4.x = m01.x; m4.y = m01.y; m4.z = m23.x; m4.w = m23.y;
    m4.x = fmaxf(m4.x, __shfl_xor(m4.x, 16, 64));
    m4.y = fmaxf(m4.y, __shfl_xor(m4.y, 16, 64));
    m4.z = fmaxf(m4.z, __shfl_xor(m4.z, 16, 64));
    m4.w = fmaxf(m4.w, __shfl_xor(m4.w, 16, 64));
    m4.x = fmaxf(m4.x, __shfl_xor(m4.x, 32, 64));
    m4.y = fmaxf(m4.y, __shfl_xor(m4.y, 32, 64));
    m4.z = fmaxf(m4.z, __shfl_xor(m4.z, 32, 64));
    m4.w = fmaxf(m4.w, __shfl_xor(m4.w, 32, 64));
    if (lane < 16) ext[(size_t)k * 16 + q] = m4;
  }

  // ---- block partials ----
  // unpack packed q2: order xx,xy,xz,xw,yy,yz,yw,zz,zw,ww
  float q2[10];
  q2[0] = pA.x; q2[1] = e0;   q2[2] = pB.x; q2[3] = pC.x; q2[4] = pA.y;
  q2[5] = pC.y; q2[6] = pB.y; q2[7] = pD.x; q2[8] = e1;   q2[9] = pD.y;
  if (lane < 54 && (lane < 4 || lane >= 14)) red[wid][lane] = oacc;
#pragma unroll
  for (int i = 0; i < 10; ++i) q2[i] = wred63(q2[i]);
  if (lane == 63) {
#pragma unroll
    for (int i = 0; i < 10; ++i) red[wid][4 + i] = q2[i];
  }
  __syncthreads();
  const int t = threadIdx.x;
  if (t < 54) {
    p54[t * NBLK + blockIdx.x] =
        red[0][t] + red[1][t] + red[2][t] + red[3][t];
  }
}

// ---------------- K2: reduce + assemble + scale/shift (512 thr) ----------
__global__ void __launch_bounds__(512) pfn_finalize(
    const float* __restrict__ p54, const float* __restrict__ W,
    const float* __restrict__ gamma, const float* __restrict__ beta,
    float invN, float* __restrict__ ss) {
  __shared__ float msum[54];
  __shared__ float m54[54];
  const int t = threadIdx.x;
  const int r = t >> 3, j = t & 7;  // 8 threads per row
  if (r < 54) {
    const int chunk = NBLK >> 3;
    const float* row = p54 + (size_t)r * NBLK + j * chunk;
    float a0 = 0, a1 = 0, a2 = 0, a3 = 0, a4 = 0, a5 = 0, a6 = 0, a7 = 0;
    int b = 0;
    for (; b + 8 <= chunk; b += 8) {
      a0 += row[b];     a1 += row[b + 1]; a2 += row[b + 2]; a3 += row[b + 3];
      a4 += row[b + 4]; a5 += row[b + 5]; a6 += row[b + 6]; a7 += row[b + 7];
    }
    for (; b < chunk; ++b) a0 += row[b];
    float s = ((a0 + a1) + (a2 + a3)) + ((a4 + a5) + (a6 + a7));
    s += __shfl_xor(s, 1, 64);
    s += __shfl_xor(s, 2, 64);
    s += __shfl_xor(s, 4, 64);
    if (j == 0) msum[r] = s;
  }
  __syncthreads();
  // msum: [0..3]=Q1 [4..13]=Q2 [14..33]=S [34..38]=U1 [39..53]=U2
  if (t < 54) {
    float v;
    if (t < 9) {
      const int g2 = (t < 4) ? t : (t < 7 ? t - 4 : t - 7);
      v = msum[g2];
      if (t >= 4) v += msum[34 + (t - 4)];
    } else {
      int r2 = t - 9, c = 0;
      while (r2 >= 9 - c) { r2 -= 9 - c; ++c; }
      const int c2 = c + r2;
      const int a = (c < 4) ? c : (c < 7 ? c - 4 : c - 7);
      const int b2 = (c2 < 4) ? c2 : (c2 < 7 ? c2 - 4 : c2 - 7);
      const int lo = a < b2 ? a : b2, hi = a < b2 ? b2 : a;
      v = msum[4 + lo * (9 - lo) / 2 + (hi - lo)];  // 4x4 tri offsets 0/4/7/9
      if (c2 >= 4) v += msum[14 + a * 5 + (c2 - 4)];
      if (c >= 4) v += msum[14 + b2 * 5 + (c - 4)];
      if (c >= 4 && c2 >= 4) {
        const int ua = c - 4, ub = c2 - 4;  // ua <= ub
        v += msum[39 + ua * 5 - ua * (ua - 1) / 2 + (ub - ua)];
      }
    }
    m54[t] = v;
  }
  __syncthreads();
  if (t < 64) {
    float wc[9];
#pragma unroll
    for (int c = 0; c < 9; ++c) wc[c] = W[c * 64 + t];
    float mu = 0.f;
#pragma unroll
    for (int c = 0; c < 9; ++c) mu += m54[c] * invN * wc[c];
    float ex2 = 0.f;
    int idx = 9;
#pragma unroll
    for (int c = 0; c < 9; ++c)
#pragma unroll
      for (int c2 = c; c2 < 9; ++c2) {
        float v = m54[idx] * invN * wc[c] * wc[c2];
        ex2 += (c == c2) ? v : 2.f * v;
        ++idx;
      }
    const float var = ex2 - mu * mu;
    const float scale = gamma[t] * rsqrtf(var + 1e-3f);
    ss[t] = scale;
    ss[64 + t] = beta[t] - mu * scale;
  }
}

// ---------------- K3: bias + un-fold + BN + relu ----------------
__global__ void __launch_bounds__(256) pfn_apply(
    const float4* __restrict__ ext, const float4* __restrict__ rec,
    const int* __restrict__ coors, const float* __restrict__ W,
    const float* __restrict__ ss, int K, int P, float4* __restrict__ out) {
  const int t = blockIdx.x * 256 + threadIdx.x;
  if (t >= K * 16) return;
  const int k = t >> 4, j = t & 15;

  const float4* Wq = (const float4*)W;  // [9][16]
  const float4 v4 = Wq[4 * 16 + j], v5 = Wq[5 * 16 + j];
  const float4 v6 = Wq[6 * 16 + j], v7 = Wq[7 * 16 + j];
  const float4 v8 = Wq[8 * 16 + j];

  const float4 e = ext[t];
  const float4 rb = rec[2 * (size_t)k + 1];
  const float nvf = rb.w, inv = 1.f / nvf;
  const float cx = (float)coors[k * 4 + 3] * 0.2f + 0.1f;
  const float cy = (float)coors[k * 4 + 2] * 0.2f - 39.9f;
  const float o0 = -rb.x * inv, o1 = -rb.y * inv, o2 = -rb.z * inv;
  float4 bias;
  bias.x = v4.x * o0 + v5.x * o1 + v6.x * o2 - v7.x * cx - v8.x * cy;
  bias.y = v4.y * o0 + v5.y * o1 + v6.y * o2 - v7.y * cx - v8.y * cy;
  bias.z = v4.z * o0 + v5.z * o1 + v6.z * o2 - v7.z * cx - v8.z * cy;
  bias.w = v4.w * o0 + v5.w * o1 + v6.w * o2 - v7.w * cx - v8.w * cy;

  const float4 sc = ((const float4*)ss)[j];
  const float4 sh = ((const float4*)(ss + 64))[j];
  const bool masked = nvf < (float)P;

  float4 o;
  {
    const float sgn = (sc.x >= 0.f) ? 1.f : -1.f;
    float ev = sgn * e.x + bias.x;
    if (masked) ev = (sc.x >= 0.f) ? fmaxf(ev, 0.f) : fminf(ev, 0.f);
    o.x = fmaxf(fmaf(sc.x, ev, sh.x), 0.f);
  }
  {
    const float sgn = (sc.y >= 0.f) ? 1.f : -1.f;
    float ev = sgn * e.y + bias.y;
    if (masked) ev = (sc.y >= 0.f) ? fmaxf(ev, 0.f) : fminf(ev, 0.f);
    o.y = fmaxf(fmaf(sc.y, ev, sh.y), 0.f);
  }
  {
    const float sgn = (sc.z >= 0.f) ? 1.f : -1.f;
    float ev = sgn * e.z + bias.z;
    if (masked) ev = (sc.z >= 0.f) ? fmaxf(ev, 0.f) : fminf(ev, 0.f);
    o.z = fmaxf(fmaf(sc.z, ev, sh.z), 0.f);
  }
  {
    const float sgn = (sc.w >= 0.f) ? 1.f : -1.f;
    float ev = sgn * e.w + bias.w;
    if (masked) ev = (sc.w >= 0.f) ? fmaxf(ev, 0.f) : fminf(ev, 0.f);
    o.w = fmaxf(fmaf(sc.w, ev, sh.w), 0.f);
  }
  out[t] = o;
}

extern "C" void kernel_launch(void* const* d_in, const int* in_sizes, int n_in,
                              void* d_out, int out_size, void* d_ws,
                              size_t ws_size, hipStream_t stream) {
  const float4* feat = (const float4*)d_in[0];
  const int* nvox = (const int*)d_in[1];
  const int* coors = (const int*)d_in[2];
  const float* W = (const float*)d_in[3];
  const float* gamma = (const float*)d_in[4];
  const float* beta = (const float*)d_in[5];

  const int K = in_sizes[1];
  const int P = in_sizes[0] / (K * 4);

  // ws layout (floats): ss[128] | ext[K*16 f4] | rec[K*2 f4] | p54[54*NBLK]
  float* ss = (float*)d_ws;
  float4* ext = (float4*)(ss + 128);
  float4* rec = ext + (size_t)K * 16;
  float* p54 = (float*)(rec + (size_t)K * 2);

  const int nwaves = NBLK * 4;
  const int cnt = (K + nwaves - 1) / nwaves;  // contiguous pillars per wave

  pfn_main<<<NBLK, 256, 0, stream>>>(feat, nvox, coors, K, P, cnt, W, gamma,
                                     p54, ext, rec);
  pfn_finalize<<<1, 512, 0, stream>>>(p54, W, gamma, beta,
                                      1.0f / (float)((long long)K * P), ss);
  pfn_apply<<<(K * 16 + 255) / 256, 256, 0, stream>>>(ext, rec, coors, W, ss,
                                                      K, P, (float4*)d_out);
}

// Round 17
// 47.272 us; speedup vs baseline: 1.1133x; 1.1133x over previous
//
#include <hip/hip_runtime.h>

// PillarFeatureNet fused, 3 kernels, single feature read, 256-thr blocks.
// R17 = R15 (best, 42.8us) + 2-way pillar ILP in K1 (pairs of pillars
// processed concurrently: overlapped loads, interleaved DPP reduction
// chains, dual LDS buffers). No forced launch bounds, scalar extrema math.
//  K1 pfn_main: wave per pillar-pair: stage to LDS; per-lane raw second
//     moments q2[10]; pure-DPP reductions + readlane(63) (zero DS ops)
//     -> rec[k] + lane-parallel cross-moments (single oacc register);
//     channel-quad sign(gamma)-folded MAX extrema (1 ds_read_b128 = 4 pts
//     x 64 ch). Block partials -> uniform p54[54][NBLK].
//  K2 pfn_finalize: reduce p54 rows, assemble 54 augmented moments
//     (verified index maps), per-channel scale/shift -> ss.
//  K3 pfn_apply: bias from rec, un-fold by sign(scale), mask clamp, BN+relu.
// p54 rows: [0..3]=Q1 [4..13]=Q2 [14..33]=S [34..38]=U1 [39..53]=U2
// features [K,P,4] f32, num_voxels [K] i32, coors [K,4] i32,
// W [9,64] f32, gamma/beta [64] f32 -> out [K,64] f32.

#define NBLK 1280  // K1 blocks (divisible by 4 for K2 chunking)

// Pure-DPP wave sum; lane 63 holds the wave total. Zero DS ops.
__device__ __forceinline__ float wred63(float v) {
  int t;
  t = __builtin_amdgcn_update_dpp(0, __float_as_int(v), 0xB1, 0xf, 0xf, true);
  v += __int_as_float(t);  // quad_perm xor1
  t = __builtin_amdgcn_update_dpp(0, __float_as_int(v), 0x4E, 0xf, 0xf, true);
  v += __int_as_float(t);  // quad_perm xor2
  t = __builtin_amdgcn_update_dpp(0, __float_as_int(v), 0x141, 0xf, 0xf, true);
  v += __int_as_float(t);  // row_half_mirror = xor7
  t = __builtin_amdgcn_update_dpp(0, __float_as_int(v), 0x140, 0xf, 0xf, true);
  v += __int_as_float(t);  // row_mirror = xor15 -> row sums
  t = __builtin_amdgcn_update_dpp(0, __float_as_int(v), 0x142, 0xa, 0xf, true);
  v += __int_as_float(t);  // row_bcast15 -> rows 1,3
  t = __builtin_amdgcn_update_dpp(0, __float_as_int(v), 0x143, 0xc, 0xf, true);
  v += __int_as_float(t);  // row_bcast31 -> rows 2,3 (lane63 total)
  return v;
}
__device__ __forceinline__ float wsum_bcast(float v) {
  return __int_as_float(
      __builtin_amdgcn_readlane(__float_as_int(wred63(v)), 63));
}

// ---------------- K1 ----------------
__global__ void __launch_bounds__(256) pfn_main(
    const float4* __restrict__ feat, const int* __restrict__ nvox,
    const int* __restrict__ coors, int K, int P, int cnt,
    const float* __restrict__ W, const float* __restrict__ gamma,
    float* __restrict__ p54, float4* __restrict__ ext,
    float4* __restrict__ rec) {
  __shared__ float4 pts[4][2][108];
  __shared__ float red[4][56];
  const int lane = threadIdx.x & 63;
  const int wid = threadIdx.x >> 6;
  const int q = lane & 15;  // channel quad (channels 4q..4q+3)
  const int g = lane >> 4;  // point group 0..3

  // ---- moment-row decode for this lane (constant) ----
  int sa = 0, sb = 0, ub = 0, ub2 = 0;
  if (lane >= 14 && lane < 34) { sa = (lane - 14) / 5; sb = (lane - 14) % 5; }
  if (lane >= 39 && lane < 54) {
    int r2 = lane - 39, b = 0;
    while (r2 >= 5 - b) { r2 -= 5 - b; ++b; }
    ub = b; ub2 = b + r2;
  }

  // ---- sign(gamma)-folded weight quads (sequential, low reg peak) ----
  const float4* Wq = (const float4*)W;  // [9][16]
  const float4 g4 = ((const float4*)gamma)[q];
  float4 sg;
  sg.x = (g4.x >= 0.f) ? 1.f : -1.f;
  sg.y = (g4.y >= 0.f) ? 1.f : -1.f;
  sg.z = (g4.z >= 0.f) ? 1.f : -1.f;
  sg.w = (g4.w >= 0.f) ? 1.f : -1.f;
  float4 wx, wy, wz, w3;
  {
    float4 t0 = Wq[0 * 16 + q], t1 = Wq[4 * 16 + q], t2 = Wq[7 * 16 + q];
    wx.x = (t0.x + t1.x + t2.x) * sg.x; wx.y = (t0.y + t1.y + t2.y) * sg.y;
    wx.z = (t0.z + t1.z + t2.z) * sg.z; wx.w = (t0.w + t1.w + t2.w) * sg.w;
  }
  {
    float4 t0 = Wq[1 * 16 + q], t1 = Wq[5 * 16 + q], t2 = Wq[8 * 16 + q];
    wy.x = (t0.x + t1.x + t2.x) * sg.x; wy.y = (t0.y + t1.y + t2.y) * sg.y;
    wy.z = (t0.z + t1.z + t2.z) * sg.z; wy.w = (t0.w + t1.w + t2.w) * sg.w;
  }
  {
    float4 t0 = Wq[2 * 16 + q], t1 = Wq[6 * 16 + q];
    wz.x = (t0.x + t1.x) * sg.x; wz.y = (t0.y + t1.y) * sg.y;
    wz.z = (t0.z + t1.z) * sg.z; wz.w = (t0.w + t1.w) * sg.w;
  }
  {
    float4 t0 = Wq[3 * 16 + q];
    w3.x = t0.x * sg.x; w3.y = t0.y * sg.y;
    w3.z = t0.z * sg.z; w3.w = t0.w * sg.w;
  }

  float q2[10] = {0, 0, 0, 0, 0, 0, 0, 0, 0, 0};
  float oacc = 0.f;

  const int gw = blockIdx.x * 4 + wid;
  const int k0 = gw * cnt;
  const int kend = (k0 + cnt < K) ? k0 + cnt : K;
  const bool hih = lane < (P - 64);  // P in (64,128]

  // ---- per-lane stats helper (macro keeps regs in scope) ----
#define STATS_ACCUM(f0_, f1_, nv_, sax_, say_, saz_, svx_, svy_, svz_, svw_) \
  {                                                                          \
    sax_ = f0_.x; say_ = f0_.y; saz_ = f0_.z;                                \
    svx_ = 0; svy_ = 0; svz_ = 0; svw_ = 0;                                  \
    if (lane < nv_) {                                                        \
      svx_ = f0_.x; svy_ = f0_.y; svz_ = f0_.z; svw_ = f0_.w;                \
      q2[0] = fmaf(f0_.x, f0_.x, q2[0]); q2[1] = fmaf(f0_.x, f0_.y, q2[1]);  \
      q2[2] = fmaf(f0_.x, f0_.z, q2[2]); q2[3] = fmaf(f0_.x, f0_.w, q2[3]);  \
      q2[4] = fmaf(f0_.y, f0_.y, q2[4]); q2[5] = fmaf(f0_.y, f0_.z, q2[5]);  \
      q2[6] = fmaf(f0_.y, f0_.w, q2[6]); q2[7] = fmaf(f0_.z, f0_.z, q2[7]);  \
      q2[8] = fmaf(f0_.z, f0_.w, q2[8]); q2[9] = fmaf(f0_.w, f0_.w, q2[9]);  \
    }                                                                        \
    if (hih) {                                                               \
      sax_ += f1_.x; say_ += f1_.y; saz_ += f1_.z;                           \
      if (64 + lane < nv_) {                                                 \
        svx_ += f1_.x; svy_ += f1_.y; svz_ += f1_.z; svw_ += f1_.w;          \
        q2[0] = fmaf(f1_.x, f1_.x, q2[0]); q2[1] = fmaf(f1_.x, f1_.y, q2[1]);\
        q2[2] = fmaf(f1_.x, f1_.z, q2[2]); q2[3] = fmaf(f1_.x, f1_.w, q2[3]);\
        q2[4] = fmaf(f1_.y, f1_.y, q2[4]); q2[5] = fmaf(f1_.y, f1_.z, q2[5]);\
        q2[6] = fmaf(f1_.y, f1_.w, q2[6]); q2[7] = fmaf(f1_.z, f1_.z, q2[7]);\
        q2[8] = fmaf(f1_.z, f1_.w, q2[8]); q2[9] = fmaf(f1_.w, f1_.w, q2[9]);\
      }                                                                      \
    }                                                                        \
  }

  // cross-moment lane-parallel add for one pillar
#define CROSS_ACCUM(nvf_, vx_, vy_, vz_, vw_, o0_, o1_, o2_, o3_, o4_)       \
  {                                                                          \
    float add = 0.f;                                                         \
    if (lane < 4) {                                                          \
      add = (lane == 0) ? vx_ : (lane == 1) ? vy_ : (lane == 2) ? vz_ : vw_; \
    } else if (lane >= 14 && lane < 34) {                                    \
      const float sva = (sa == 0) ? vx_ : (sa == 1) ? vy_                    \
                      : (sa == 2) ? vz_ : vw_;                               \
      const float ob = (sb == 0) ? o0_ : (sb == 1) ? o1_                     \
                     : (sb == 2) ? o2_ : (sb == 3) ? o3_ : o4_;              \
      add = sva * ob;                                                        \
    } else if (lane >= 34 && lane < 39) {                                    \
      const int b = lane - 34;                                               \
      const float ob = (b == 0) ? o0_ : (b == 1) ? o1_                       \
                     : (b == 2) ? o2_ : (b == 3) ? o3_ : o4_;                \
      add = nvf_ * ob;                                                       \
    } else if (lane >= 39 && lane < 54) {                                    \
      const float oa = (ub == 0) ? o0_ : (ub == 1) ? o1_                     \
                     : (ub == 2) ? o2_ : (ub == 3) ? o3_ : o4_;              \
      const float ob = (ub2 == 0) ? o0_ : (ub2 == 1) ? o1_                   \
                     : (ub2 == 2) ? o2_ : (ub2 == 3) ? o3_ : o4_;            \
      add = nvf_ * oa * ob;                                                  \
    }                                                                        \
    oacc += add;                                                             \
  }

  // extrema for one staged pillar buffer
#define EXTREMA(buf_, nv_, kk_)                                              \
  {                                                                          \
    float4 m4 = {-3e38f, -3e38f, -3e38f, -3e38f};                            \
    int p = 0;                                                               \
    for (; p + 8 <= nv_; p += 8) {                                           \
      const float4 fa = pts[wid][buf_][p + g];                               \
      const float4 fb = pts[wid][buf_][p + 4 + g];                           \
      m4.x = fmaxf(m4.x, fmaf(fa.x, wx.x, fmaf(fa.y, wy.x, fmaf(fa.z, wz.x, fa.w * w3.x)))); \
      m4.y = fmaxf(m4.y, fmaf(fa.x, wx.y, fmaf(fa.y, wy.y, fmaf(fa.z, wz.y, fa.w * w3.y)))); \
      m4.z = fmaxf(m4.z, fmaf(fa.x, wx.z, fmaf(fa.y, wy.z, fmaf(fa.z, wz.z, fa.w * w3.z)))); \
      m4.w = fmaxf(m4.w, fmaf(fa.x, wx.w, fmaf(fa.y, wy.w, fmaf(fa.z, wz.w, fa.w * w3.w)))); \
      m4.x = fmaxf(m4.x, fmaf(fb.x, wx.x, fmaf(fb.y, wy.x, fmaf(fb.z, wz.x, fb.w * w3.x)))); \
      m4.y = fmaxf(m4.y, fmaf(fb.x, wx.y, fmaf(fb.y, wy.y, fmaf(fb.z, wz.y, fb.w * w3.y)))); \
      m4.z = fmaxf(m4.z, fmaf(fb.x, wx.z, fmaf(fb.y, wy.z, fmaf(fb.z, wz.z, fb.w * w3.z)))); \
      m4.w = fmaxf(m4.w, fmaf(fb.x, wx.w, fmaf(fb.y, wy.w, fmaf(fb.z, wz.w, fb.w * w3.w)))); \
    }                                                                        \
    if (p < nv_) {                                                           \
      const int i0 = p + g, i1 = p + 4 + g;                                  \
      const float4 fa = pts[wid][buf_][i0];                                  \
      const float4 fb = pts[wid][buf_][i1];                                  \
      if (i0 < nv_) {                                                        \
        m4.x = fmaxf(m4.x, fmaf(fa.x, wx.x, fmaf(fa.y, wy.x, fmaf(fa.z, wz.x, fa.w * w3.x)))); \
        m4.y = fmaxf(m4.y, fmaf(fa.x, wx.y, fmaf(fa.y, wy.y, fmaf(fa.z, wz.y, fa.w * w3.y)))); \
        m4.z = fmaxf(m4.z, fmaf(fa.x, wx.z, fmaf(fa.y, wy.z, fmaf(fa.z, wz.z, fa.w * w3.z)))); \
        m4.w = fmaxf(m4.w, fmaf(fa.x, wx.w, fmaf(fa.y, wy.w, fmaf(fa.z, wz.w, fa.w * w3.w)))); \
      }                                                                      \
      if (i1 < nv_) {                                                        \
        m4.x = fmaxf(m4.x, fmaf(fb.x, wx.x, fmaf(fb.y, wy.x, fmaf(fb.z, wz.x, fb.w * w3.x)))); \
        m4.y = fmaxf(m4.y, fmaf(fb.x, wx.y, fmaf(fb.y, wy.y, fmaf(fb.z, wz.y, fb.w * w3.y)))); \
        m4.z = fmaxf(m4.z, fmaf(fb.x, wx.z, fmaf(fb.y, wy.z, fmaf(fb.z, wz.z, fb.w * w3.z)))); \
        m4.w = fmaxf(m4.w, fmaf(fb.x, wx.w, fmaf(fb.y, wy.w, fmaf(fb.z, wz.w, fb.w * w3.w)))); \
      }                                                                      \
    }                                                                        \
    m4.x = fmaxf(m4.x, __shfl_xor(m4.x, 16, 64));                            \
    m4.y = fmaxf(m4.y, __shfl_xor(m4.y, 16, 64));                            \
    m4.z = fmaxf(m4.z, __shfl_xor(m4.z, 16, 64));                            \
    m4.w = fmaxf(m4.w, __shfl_xor(m4.w, 16, 64));                            \
    m4.x = fmaxf(m4.x, __shfl_xor(m4.x, 32, 64));                            \
    m4.y = fmaxf(m4.y, __shfl_xor(m4.y, 32, 64));                            \
    m4.z = fmaxf(m4.z, __shfl_xor(m4.z, 32, 64));                            \
    m4.w = fmaxf(m4.w, __shfl_xor(m4.w, 32, 64));                            \
    if (lane < 16) ext[(size_t)(kk_) * 16 + q] = m4;                         \
  }

  int k = k0;
  for (; k + 1 < kend; k += 2) {
    // ---- both pillars' loads issued together (latency overlap) ----
    const size_t ba = (size_t)k * P, bb = (size_t)(k + 1) * P;
    const float4 f0a = feat[ba + lane];
    const float4 f0b = feat[bb + lane];
    float4 f1a, f1b;
    if (hih) { f1a = feat[ba + 64 + lane]; f1b = feat[bb + 64 + lane]; }
    const int nva = nvox[k], nvb = nvox[k + 1];

    // stage both
    pts[wid][0][lane] = f0a;
    pts[wid][1][lane] = f0b;
    if (hih) {
      pts[wid][0][64 + lane] = f1a;
      pts[wid][1][64 + lane] = f1b;
    }

    // per-lane stats, both pillars
    float saxa, saya, saza, svxa, svya, svza, svwa;
    float saxb, sayb, sazb, svxb, svyb, svzb, svwb;
    STATS_ACCUM(f0a, f1a, nva, saxa, saya, saza, svxa, svya, svza, svwa);
    STATS_ACCUM(f0b, f1b, nvb, saxb, sayb, sazb, svxb, svyb, svzb, svwb);

    // 14 independent DPP reduction chains (scheduler interleaves)
    const float rxa = wsum_bcast(saxa), rxb = wsum_bcast(saxb);
    const float rya = wsum_bcast(saya), ryb = wsum_bcast(sayb);
    const float rza = wsum_bcast(saza), rzb = wsum_bcast(sazb);
    const float vxa = wsum_bcast(svxa), vxb = wsum_bcast(svxb);
    const float vya = wsum_bcast(svya), vyb = wsum_bcast(svyb);
    const float vza = wsum_bcast(svza), vzb = wsum_bcast(svzb);
    const float vwa = wsum_bcast(svwa), vwb = wsum_bcast(svwb);

    const float nvfa = (float)nva, inva = 1.f / nvfa;
    const float nvfb = (float)nvb, invb = 1.f / nvfb;
    const float cxa = (float)coors[k * 4 + 3] * 0.2f + 0.1f;
    const float cya = (float)coors[k * 4 + 2] * 0.2f - 39.9f;
    const float cxb = (float)coors[(k + 1) * 4 + 3] * 0.2f + 0.1f;
    const float cyb = (float)coors[(k + 1) * 4 + 2] * 0.2f - 39.9f;
    const float o0a = -rxa * inva, o1a = -rya * inva, o2a = -rza * inva;
    const float o0b = -rxb * invb, o1b = -ryb * invb, o2b = -rzb * invb;

    CROSS_ACCUM(nvfa, vxa, vya, vza, vwa, o0a, o1a, o2a, -cxa, -cya);
    CROSS_ACCUM(nvfb, vxb, vyb, vzb, vwb, o0b, o1b, o2b, -cxb, -cyb);

    if (lane == 0) {
      float4 r0, r1;
      r0.x = vxa; r0.y = vya; r0.z = vza; r0.w = vwa;
      r1.x = rxa; r1.y = rya; r1.z = rza; r1.w = nvfa;
      rec[2 * (size_t)k] = r0;
      rec[2 * (size_t)k + 1] = r1;
      r0.x = vxb; r0.y = vyb; r0.z = vzb; r0.w = vwb;
      r1.x = rxb; r1.y = ryb; r1.z = rzb; r1.w = nvfb;
      rec[2 * (size_t)(k + 1)] = r0;
      rec[2 * (size_t)(k + 1) + 1] = r1;
    }

    EXTREMA(0, nva, k);
    EXTREMA(1, nvb, k + 1);
  }
  if (k < kend) {  // odd tail pillar
    const size_t base = (size_t)k * P;
    const float4 f0 = feat[base + lane];
    float4 f1;
    if (hih) f1 = feat[base + 64 + lane];
    const int nv = nvox[k];
    pts[wid][0][lane] = f0;
    if (hih) pts[wid][0][64 + lane] = f1;

    float sax, say, saz, svx, svy, svz, svw;
    STATS_ACCUM(f0, f1, nv, sax, say, saz, svx, svy, svz, svw);
    const float rx = wsum_bcast(sax), ry = wsum_bcast(say);
    const float rz = wsum_bcast(saz);
    const float vx = wsum_bcast(svx), vy = wsum_bcast(svy);
    const float vz = wsum_bcast(svz), vw = wsum_bcast(svw);
    const float nvf = (float)nv, inv = 1.f / nvf;
    const float cx = (float)coors[k * 4 + 3] * 0.2f + 0.1f;
    const float cy = (float)coors[k * 4 + 2] * 0.2f - 39.9f;
    const float o0 = -rx * inv, o1 = -ry * inv, o2 = -rz * inv;
    CROSS_ACCUM(nvf, vx, vy, vz, vw, o0, o1, o2, -cx, -cy);
    if (lane == 0) {
      float4 r0, r1;
      r0.x = vx; r0.y = vy; r0.z = vz; r0.w = vw;
      r1.x = rx; r1.y = ry; r1.z = rz; r1.w = nvf;
      rec[2 * (size_t)k] = r0;
      rec[2 * (size_t)k + 1] = r1;
    }
    EXTREMA(0, nv, k);
  }

  // ---- block partials: rows 0..3,14..53 from oacc; 4..13 from q2 ----
  if (lane < 54 && (lane < 4 || lane >= 14)) red[wid][lane] = oacc;
#pragma unroll
  for (int i = 0; i < 10; ++i) q2[i] = wred63(q2[i]);
  if (lane == 63) {
#pragma unroll
    for (int i = 0; i < 10; ++i) red[wid][4 + i] = q2[i];
  }
  __syncthreads();
  const int t = threadIdx.x;
  if (t < 54) {
    p54[t * NBLK + blockIdx.x] =
        red[0][t] + red[1][t] + red[2][t] + red[3][t];
  }
}

// ---------------- K2: reduce + assemble + scale/shift ----------------
__global__ void __launch_bounds__(256) pfn_finalize(
    const float* __restrict__ p54, const float* __restrict__ W,
    const float* __restrict__ gamma, const float* __restrict__ beta,
    float invN, float* __restrict__ ss) {
  __shared__ float msum[54];
  __shared__ float m54[54];
  const int t = threadIdx.x;
  const int r = t >> 2, j = t & 3;
  if (r < 54) {
    const int chunk = NBLK >> 2;
    const float* row = p54 + (size_t)r * NBLK + j * chunk;
    float a0 = 0, a1 = 0, a2 = 0, a3 = 0, a4 = 0, a5 = 0, a6 = 0, a7 = 0;
    int b = 0;
    for (; b + 8 <= chunk; b += 8) {
      a0 += row[b];     a1 += row[b + 1]; a2 += row[b + 2]; a3 += row[b + 3];
      a4 += row[b + 4]; a5 += row[b + 5]; a6 += row[b + 6]; a7 += row[b + 7];
    }
    for (; b < chunk; ++b) a0 += row[b];
    float s = ((a0 + a1) + (a2 + a3)) + ((a4 + a5) + (a6 + a7));
    s += __shfl_xor(s, 1, 64);
    s += __shfl_xor(s, 2, 64);
    if (j == 0) msum[r] = s;
  }
  __syncthreads();
  // msum: [0..3]=Q1 [4..13]=Q2 [14..33]=S [34..38]=U1 [39..53]=U2
  if (t < 54) {
    float v;
    if (t < 9) {
      const int g2 = (t < 4) ? t : (t < 7 ? t - 4 : t - 7);
      v = msum[g2];
      if (t >= 4) v += msum[34 + (t - 4)];
    } else {
      int r2 = t - 9, c = 0;
      while (r2 >= 9 - c) { r2 -= 9 - c; ++c; }
      const int c2 = c + r2;
      const int a = (c < 4) ? c : (c < 7 ? c - 4 : c - 7);
      const int b2 = (c2 < 4) ? c2 : (c2 < 7 ? c2 - 4 : c2 - 7);
      const int lo = a < b2 ? a : b2, hi = a < b2 ? b2 : a;
      v = msum[4 + lo * (9 - lo) / 2 + (hi - lo)];  // 4x4 tri offsets 0/4/7/9
      if (c2 >= 4) v += msum[14 + a * 5 + (c2 - 4)];
      if (c >= 4) v += msum[14 + b2 * 5 + (c - 4)];
      if (c >= 4 && c2 >= 4) {
        const int ua = c - 4, ub = c2 - 4;  // ua <= ub
        v += msum[39 + ua * 5 - ua * (ua - 1) / 2 + (ub - ua)];
      }
    }
    m54[t] = v;
  }
  __syncthreads();
  if (t < 64) {
    float wc[9];
#pragma unroll
    for (int c = 0; c < 9; ++c) wc[c] = W[c * 64 + t];
    float mu = 0.f;
#pragma unroll
    for (int c = 0; c < 9; ++c) mu += m54[c] * invN * wc[c];
    float ex2 = 0.f;
    int idx = 9;
#pragma unroll
    for (int c = 0; c < 9; ++c)
#pragma unroll
      for (int c2 = c; c2 < 9; ++c2) {
        float v = m54[idx] * invN * wc[c] * wc[c2];
        ex2 += (c == c2) ? v : 2.f * v;
        ++idx;
      }
    const float var = ex2 - mu * mu;
    const float scale = gamma[t] * rsqrtf(var + 1e-3f);
    ss[t] = scale;
    ss[64 + t] = beta[t] - mu * scale;
  }
}

// ---------------- K3: bias + un-fold + BN + relu ----------------
__global__ void __launch_bounds__(256) pfn_apply(
    const float4* __restrict__ ext, const float4* __restrict__ rec,
    const int* __restrict__ coors, const float* __restrict__ W,
    const float* __restrict__ ss, int K, int P, float4* __restrict__ out) {
  const int t = blockIdx.x * 256 + threadIdx.x;
  if (t >= K * 16) return;
  const int k = t >> 4, j = t & 15;

  const float4* Wq = (const float4*)W;  // [9][16]
  const float4 v4 = Wq[4 * 16 + j], v5 = Wq[5 * 16 + j];
  const float4 v6 = Wq[6 * 16 + j], v7 = Wq[7 * 16 + j];
  const float4 v8 = Wq[8 * 16 + j];

  const float4 e = ext[t];
  const float4 rb = rec[2 * (size_t)k + 1];
  const float nvf = rb.w, inv = 1.f / nvf;
  const float cx = (float)coors[k * 4 + 3] * 0.2f + 0.1f;
  const float cy = (float)coors[k * 4 + 2] * 0.2f - 39.9f;
  const float o0 = -rb.x * inv, o1 = -rb.y * inv, o2 = -rb.z * inv;
  float4 bias;
  bias.x = v4.x * o0 + v5.x * o1 + v6.x * o2 - v7.x * cx - v8.x * cy;
  bias.y = v4.y * o0 + v5.y * o1 + v6.y * o2 - v7.y * cx - v8.y * cy;
  bias.z = v4.z * o0 + v5.z * o1 + v6.z * o2 - v7.z * cx - v8.z * cy;
  bias.w = v4.w * o0 + v5.w * o1 + v6.w * o2 - v7.w * cx - v8.w * cy;

  const float4 sc = ((const float4*)ss)[j];
  const float4 sh = ((const float4*)(ss + 64))[j];
  const bool masked = nvf < (float)P;

  float4 o;
  {
    const float sgn = (sc.x >= 0.f) ? 1.f : -1.f;
    float ev = sgn * e.x + bias.x;
    if (masked) ev = (sc.x >= 0.f) ? fmaxf(ev, 0.f) : fminf(ev, 0.f);
    o.x = fmaxf(fmaf(sc.x, ev, sh.x), 0.f);
  }
  {
    const float sgn = (sc.y >= 0.f) ? 1.f : -1.f;
    float ev = sgn * e.y + bias.y;
    if (masked) ev = (sc.y >= 0.f) ? fmaxf(ev, 0.f) : fminf(ev, 0.f);
    o.y = fmaxf(fmaf(sc.y, ev, sh.y), 0.f);
  }
  {
    const float sgn = (sc.z >= 0.f) ? 1.f : -1.f;
    float ev = sgn * e.z + bias.z;
    if (masked) ev = (sc.z >= 0.f) ? fmaxf(ev, 0.f) : fminf(ev, 0.f);
    o.z = fmaxf(fmaf(sc.z, ev, sh.z), 0.f);
  }
  {
    const float sgn = (sc.w >= 0.f) ? 1.f : -1.f;
    float ev = sgn * e.w + bias.w;
    if (masked) ev = (sc.w >= 0.f) ? fmaxf(ev, 0.f) : fminf(ev, 0.f);
    o.w = fmaxf(fmaf(sc.w, ev, sh.w), 0.f);
  }
  out[t] = o;
}

extern "C" void kernel_launch(void* const* d_in, const int* in_sizes, int n_in,
                              void* d_out, int out_size, void* d_ws,
                              size_t ws_size, hipStream_t stream) {
  const float4* feat = (const float4*)d_in[0];
  const int* nvox = (const int*)d_in[1];
  const int* coors = (const int*)d_in[2];
  const float* W = (const float*)d_in[3];
  const float* gamma = (const float*)d_in[4];
  const float* beta = (const float*)d_in[5];

  const int K = in_sizes[1];
  const int P = in_sizes[0] / (K * 4);

  // ws layout (floats): ss[128] | ext[K*16 f4] | rec[K*2 f4] | p54[54*NBLK]
  float* ss = (float*)d_ws;
  float4* ext = (float4*)(ss + 128);
  float4* rec = ext + (size_t)K * 16;
  float* p54 = (float*)(rec + (size_t)K * 2);

  const int nwaves = NBLK * 4;
  const int cnt = (K + nwaves - 1) / nwaves;  // contiguous pillars per wave

  pfn_main<<<NBLK, 256, 0, stream>>>(feat, nvox, coors, K, P, cnt, W, gamma,
                                     p54, ext, rec);
  pfn_finalize<<<1, 256, 0, stream>>>(p54, W, gamma, beta,
                                      1.0f / (float)((long long)K * P), ss);
  pfn_apply<<<(K * 16 + 255) / 256, 256, 0, stream>>>(ext, rec, coors, W, ss,
                                                      K, P, (float4*)d_out);
}

// Round 18
// 47.198 us; speedup vs baseline: 1.1151x; 1.0016x over previous
//
#include <hip/hip_runtime.h>

// PillarFeatureNet fused, 3 kernels, single feature read, 256-thr blocks.
// R18 = R15 (best 42.8us) + metadata hoist (nvox/coors for the whole
// cnt<=4 run loaded before the loop) + 1-deep feature prefetch (next
// pillar's loads issued under current pillar's compute). Single LDS buffer
// (same-wave DS ordering). No forced launch bounds, scalar extrema math.
//  K1 pfn_main: wave per pillar run: stage to LDS; per-lane raw second
//     moments q2[10]; pure-DPP reductions + readlane(63) (zero DS ops)
//     -> rec[k] + lane-parallel cross-moments (single oacc register);
//     channel-quad sign(gamma)-folded MAX extrema (1 ds_read_b128 = 4 pts
//     x 64 ch). Block partials -> uniform p54[54][NBLK].
//  K2 pfn_finalize: reduce p54 rows, assemble 54 augmented moments
//     (verified index maps), per-channel scale/shift -> ss.
//  K3 pfn_apply: bias from rec, un-fold by sign(scale), mask clamp, BN+relu.
// p54 rows: [0..3]=Q1 [4..13]=Q2 [14..33]=S [34..38]=U1 [39..53]=U2
// features [K,P,4] f32, num_voxels [K] i32, coors [K,4] i32,
// W [9,64] f32, gamma/beta [64] f32 -> out [K,64] f32.

#define NBLK 1280  // K1 blocks (divisible by 4); cnt = ceil(K/5120) <= 4
#define CMAX 4     // max pillars per wave (metadata hoist width)

// Pure-DPP wave sum; lane 63 holds the wave total. Zero DS ops.
__device__ __forceinline__ float wred63(float v) {
  int t;
  t = __builtin_amdgcn_update_dpp(0, __float_as_int(v), 0xB1, 0xf, 0xf, true);
  v += __int_as_float(t);  // quad_perm xor1
  t = __builtin_amdgcn_update_dpp(0, __float_as_int(v), 0x4E, 0xf, 0xf, true);
  v += __int_as_float(t);  // quad_perm xor2
  t = __builtin_amdgcn_update_dpp(0, __float_as_int(v), 0x141, 0xf, 0xf, true);
  v += __int_as_float(t);  // row_half_mirror = xor7
  t = __builtin_amdgcn_update_dpp(0, __float_as_int(v), 0x140, 0xf, 0xf, true);
  v += __int_as_float(t);  // row_mirror = xor15 -> row sums
  t = __builtin_amdgcn_update_dpp(0, __float_as_int(v), 0x142, 0xa, 0xf, true);
  v += __int_as_float(t);  // row_bcast15 -> rows 1,3
  t = __builtin_amdgcn_update_dpp(0, __float_as_int(v), 0x143, 0xc, 0xf, true);
  v += __int_as_float(t);  // row_bcast31 -> rows 2,3 (lane63 total)
  return v;
}
__device__ __forceinline__ float wsum_bcast(float v) {
  return __int_as_float(
      __builtin_amdgcn_readlane(__float_as_int(wred63(v)), 63));
}

// ---------------- K1 ----------------
__global__ void __launch_bounds__(256) pfn_main(
    const float4* __restrict__ feat, const int* __restrict__ nvox,
    const int* __restrict__ coors, int K, int P, int cnt,
    const float* __restrict__ W, const float* __restrict__ gamma,
    float* __restrict__ p54, float4* __restrict__ ext,
    float4* __restrict__ rec) {
  __shared__ float4 pts[4][108];
  __shared__ float red[4][56];
  const int lane = threadIdx.x & 63;
  const int wid = threadIdx.x >> 6;
  const int q = lane & 15;  // channel quad (channels 4q..4q+3)
  const int g = lane >> 4;  // point group 0..3

  // ---- moment-row decode for this lane (constant) ----
  int sa = 0, sb = 0, ub = 0, ub2 = 0;
  if (lane >= 14 && lane < 34) { sa = (lane - 14) / 5; sb = (lane - 14) % 5; }
  if (lane >= 39 && lane < 54) {
    int r2 = lane - 39, b = 0;
    while (r2 >= 5 - b) { r2 -= 5 - b; ++b; }
    ub = b; ub2 = b + r2;
  }

  // ---- sign(gamma)-folded weight quads (sequential, low reg peak) ----
  const float4* Wq = (const float4*)W;  // [9][16]
  const float4 g4 = ((const float4*)gamma)[q];
  float4 sg;
  sg.x = (g4.x >= 0.f) ? 1.f : -1.f;
  sg.y = (g4.y >= 0.f) ? 1.f : -1.f;
  sg.z = (g4.z >= 0.f) ? 1.f : -1.f;
  sg.w = (g4.w >= 0.f) ? 1.f : -1.f;
  float4 wx, wy, wz, w3;
  {
    float4 t0 = Wq[0 * 16 + q], t1 = Wq[4 * 16 + q], t2 = Wq[7 * 16 + q];
    wx.x = (t0.x + t1.x + t2.x) * sg.x; wx.y = (t0.y + t1.y + t2.y) * sg.y;
    wx.z = (t0.z + t1.z + t2.z) * sg.z; wx.w = (t0.w + t1.w + t2.w) * sg.w;
  }
  {
    float4 t0 = Wq[1 * 16 + q], t1 = Wq[5 * 16 + q], t2 = Wq[8 * 16 + q];
    wy.x = (t0.x + t1.x + t2.x) * sg.x; wy.y = (t0.y + t1.y + t2.y) * sg.y;
    wy.z = (t0.z + t1.z + t2.z) * sg.z; wy.w = (t0.w + t1.w + t2.w) * sg.w;
  }
  {
    float4 t0 = Wq[2 * 16 + q], t1 = Wq[6 * 16 + q];
    wz.x = (t0.x + t1.x) * sg.x; wz.y = (t0.y + t1.y) * sg.y;
    wz.z = (t0.z + t1.z) * sg.z; wz.w = (t0.w + t1.w) * sg.w;
  }
  {
    float4 t0 = Wq[3 * 16 + q];
    w3.x = t0.x * sg.x; w3.y = t0.y * sg.y;
    w3.z = t0.z * sg.z; w3.w = t0.w * sg.w;
  }

  float q2[10] = {0, 0, 0, 0, 0, 0, 0, 0, 0, 0};
  float oacc = 0.f;

  const int gw = blockIdx.x * 4 + wid;
  const int k0 = gw * cnt;
  const int kend = (k0 + cnt < K) ? k0 + cnt : K;
  const bool hih = lane < (P - 64);  // P in (64,128]
  const int nrun = kend - k0;        // 0..CMAX pillars for this wave

  // ---- metadata hoist: nvox/coors for the whole run (12 early loads) ----
  int nvA[CMAX];
  float cxA[CMAX], cyA[CMAX];
#pragma unroll
  for (int i = 0; i < CMAX; ++i) {
    const int kk = k0 + i;
    const bool ok = (i < nrun);
    nvA[i] = ok ? nvox[kk] : 1;
    cxA[i] = ok ? (float)coors[kk * 4 + 3] * 0.2f + 0.1f : 0.f;
    cyA[i] = ok ? (float)coors[kk * 4 + 2] * 0.2f - 39.9f : 0.f;
  }

  if (nrun > 0) {
    // first pillar's feature loads
    float4 f0 = feat[(size_t)k0 * P + lane];
    float4 f1;
    if (hih) f1 = feat[(size_t)k0 * P + 64 + lane];

#pragma unroll
    for (int i = 0; i < CMAX; ++i) {
      if (i >= nrun) break;
      const int k = k0 + i;
      const int nv = nvA[i];

      // ---- stage current pillar (same-wave DS ordering keeps it safe) --
      pts[wid][lane] = f0;
      if (hih) pts[wid][64 + lane] = f1;

      // ---- prefetch next pillar (lands under this pillar's compute) ----
      float4 f0n, f1n;
      if (i + 1 < nrun) {
        const size_t nb = (size_t)(k + 1) * P;
        f0n = feat[nb + lane];
        if (hih) f1n = feat[nb + 64 + lane];
      }

      // ---- per-lane sums + raw second moments (from registers) ----
      float sax = f0.x, say = f0.y, saz = f0.z;
      float svx = 0, svy = 0, svz = 0, svw = 0;
      if (lane < nv) {
        svx = f0.x; svy = f0.y; svz = f0.z; svw = f0.w;
        q2[0] = fmaf(f0.x, f0.x, q2[0]); q2[1] = fmaf(f0.x, f0.y, q2[1]);
        q2[2] = fmaf(f0.x, f0.z, q2[2]); q2[3] = fmaf(f0.x, f0.w, q2[3]);
        q2[4] = fmaf(f0.y, f0.y, q2[4]); q2[5] = fmaf(f0.y, f0.z, q2[5]);
        q2[6] = fmaf(f0.y, f0.w, q2[6]); q2[7] = fmaf(f0.z, f0.z, q2[7]);
        q2[8] = fmaf(f0.z, f0.w, q2[8]); q2[9] = fmaf(f0.w, f0.w, q2[9]);
      }
      if (hih) {
        sax += f1.x; say += f1.y; saz += f1.z;
        if (64 + lane < nv) {
          svx += f1.x; svy += f1.y; svz += f1.z; svw += f1.w;
          q2[0] = fmaf(f1.x, f1.x, q2[0]); q2[1] = fmaf(f1.x, f1.y, q2[1]);
          q2[2] = fmaf(f1.x, f1.z, q2[2]); q2[3] = fmaf(f1.x, f1.w, q2[3]);
          q2[4] = fmaf(f1.y, f1.y, q2[4]); q2[5] = fmaf(f1.y, f1.z, q2[5]);
          q2[6] = fmaf(f1.y, f1.w, q2[6]); q2[7] = fmaf(f1.z, f1.z, q2[7]);
          q2[8] = fmaf(f1.z, f1.w, q2[8]); q2[9] = fmaf(f1.w, f1.w, q2[9]);
        }
      }

      // ---- 7 pure-DPP reductions -> uniform wave totals (zero DS ops) --
      const float rx = wsum_bcast(sax);
      const float ry = wsum_bcast(say);
      const float rz = wsum_bcast(saz);
      const float vx = wsum_bcast(svx);
      const float vy = wsum_bcast(svy);
      const float vz = wsum_bcast(svz);
      const float vw = wsum_bcast(svw);

      const float nvf = (float)nv, inv = 1.f / nvf;
      const float o0 = -rx * inv, o1 = -ry * inv, o2 = -rz * inv;
      const float o3 = -cxA[i], o4 = -cyA[i];

      // ---- lane-parallel cross-moment accumulation (1 register) ----
      {
        float add = 0.f;
        if (lane < 4) {
          add = (lane == 0) ? vx : (lane == 1) ? vy : (lane == 2) ? vz : vw;
        } else if (lane >= 14 && lane < 34) {
          const float sva =
              (sa == 0) ? vx : (sa == 1) ? vy : (sa == 2) ? vz : vw;
          const float ob = (sb == 0) ? o0 : (sb == 1) ? o1
                         : (sb == 2) ? o2 : (sb == 3) ? o3 : o4;
          add = sva * ob;
        } else if (lane >= 34 && lane < 39) {
          const int b = lane - 34;
          const float ob = (b == 0) ? o0 : (b == 1) ? o1
                         : (b == 2) ? o2 : (b == 3) ? o3 : o4;
          add = nvf * ob;
        } else if (lane >= 39 && lane < 54) {
          const float oa = (ub == 0) ? o0 : (ub == 1) ? o1
                         : (ub == 2) ? o2 : (ub == 3) ? o3 : o4;
          const float ob = (ub2 == 0) ? o0 : (ub2 == 1) ? o1
                         : (ub2 == 2) ? o2 : (ub2 == 3) ? o3 : o4;
          add = nvf * oa * ob;
        }
        oacc += add;
      }

      if (lane == 0) {
        float4 r0; r0.x = vx; r0.y = vy; r0.z = vz; r0.w = vw;
        float4 r1; r1.x = rx; r1.y = ry; r1.z = rz; r1.w = nvf;
        rec[2 * (size_t)k] = r0;
        rec[2 * (size_t)k + 1] = r1;
      }

      // ---- channel-quad folded MAX extrema (verified R10 scheme) ----
      float4 m4 = {-3e38f, -3e38f, -3e38f, -3e38f};
      int p = 0;
      for (; p + 8 <= nv; p += 8) {
        const float4 fa = pts[wid][p + g];
        const float4 fb = pts[wid][p + 4 + g];
        m4.x = fmaxf(m4.x, fmaf(fa.x, wx.x, fmaf(fa.y, wy.x, fmaf(fa.z, wz.x, fa.w * w3.x))));
        m4.y = fmaxf(m4.y, fmaf(fa.x, wx.y, fmaf(fa.y, wy.y, fmaf(fa.z, wz.y, fa.w * w3.y))));
        m4.z = fmaxf(m4.z, fmaf(fa.x, wx.z, fmaf(fa.y, wy.z, fmaf(fa.z, wz.z, fa.w * w3.z))));
        m4.w = fmaxf(m4.w, fmaf(fa.x, wx.w, fmaf(fa.y, wy.w, fmaf(fa.z, wz.w, fa.w * w3.w))));
        m4.x = fmaxf(m4.x, fmaf(fb.x, wx.x, fmaf(fb.y, wy.x, fmaf(fb.z, wz.x, fb.w * w3.x))));
        m4.y = fmaxf(m4.y, fmaf(fb.x, wx.y, fmaf(fb.y, wy.y, fmaf(fb.z, wz.y, fb.w * w3.y))));
        m4.z = fmaxf(m4.z, fmaf(fb.x, wx.z, fmaf(fb.y, wy.z, fmaf(fb.z, wz.z, fb.w * w3.z))));
        m4.w = fmaxf(m4.w, fmaf(fb.x, wx.w, fmaf(fb.y, wy.w, fmaf(fb.z, wz.w, fb.w * w3.w))));
      }
      if (p < nv) {  // predicated tail octet
        const int i0 = p + g, i1 = p + 4 + g;
        const float4 fa = pts[wid][i0];
        const float4 fb = pts[wid][i1];
        if (i0 < nv) {
          m4.x = fmaxf(m4.x, fmaf(fa.x, wx.x, fmaf(fa.y, wy.x, fmaf(fa.z, wz.x, fa.w * w3.x))));
          m4.y = fmaxf(m4.y, fmaf(fa.x, wx.y, fmaf(fa.y, wy.y, fmaf(fa.z, wz.y, fa.w * w3.y))));
          m4.z = fmaxf(m4.z, fmaf(fa.x, wx.z, fmaf(fa.y, wy.z, fmaf(fa.z, wz.z, fa.w * w3.z))));
          m4.w = fmaxf(m4.w, fmaf(fa.x, wx.w, fmaf(fa.y, wy.w, fmaf(fa.z, wz.w, fa.w * w3.w))));
        }
        if (i1 < nv) {
          m4.x = fmaxf(m4.x, fmaf(fb.x, wx.x, fmaf(fb.y, wy.x, fmaf(fb.z, wz.x, fb.w * w3.x))));
          m4.y = fmaxf(m4.y, fmaf(fb.x, wx.y, fmaf(fb.y, wy.y, fmaf(fb.z, wz.y, fb.w * w3.y))));
          m4.z = fmaxf(m4.z, fmaf(fb.x, wx.z, fmaf(fb.y, wy.z, fmaf(fb.z, wz.z, fb.w * w3.z))));
          m4.w = fmaxf(m4.w, fmaf(fb.x, wx.w, fmaf(fb.y, wy.w, fmaf(fb.z, wz.w, fb.w * w3.w))));
        }
      }
      m4.x = fmaxf(m4.x, __shfl_xor(m4.x, 16, 64));
      m4.y = fmaxf(m4.y, __shfl_xor(m4.y, 16, 64));
      m4.z = fmaxf(m4.z, __shfl_xor(m4.z, 16, 64));
      m4.w = fmaxf(m4.w, __shfl_xor(m4.w, 16, 64));
      m4.x = fmaxf(m4.x, __shfl_xor(m4.x, 32, 64));
      m4.y = fmaxf(m4.y, __shfl_xor(m4.y, 32, 64));
      m4.z = fmaxf(m4.z, __shfl_xor(m4.z, 32, 64));
      m4.w = fmaxf(m4.w, __shfl_xor(m4.w, 32, 64));
      if (lane < 16) ext[(size_t)k * 16 + q] = m4;

      f0 = f0n; f1 = f1n;  // rotate prefetch
    }
  }

  // ---- block partials: rows 0..3,14..53 from oacc; 4..13 from q2 ----
  if (lane < 54 && (lane < 4 || lane >= 14)) red[wid][lane] = oacc;
#pragma unroll
  for (int i = 0; i < 10; ++i) q2[i] = wred63(q2[i]);
  if (lane == 63) {
#pragma unroll
    for (int i = 0; i < 10; ++i) red[wid][4 + i] = q2[i];
  }
  __syncthreads();
  const int t = threadIdx.x;
  if (t < 54) {
    p54[t * NBLK + blockIdx.x] =
        red[0][t] + red[1][t] + red[2][t] + red[3][t];
  }
}

// ---------------- K2: reduce + assemble + scale/shift ----------------
__global__ void __launch_bounds__(256) pfn_finalize(
    const float* __restrict__ p54, const float* __restrict__ W,
    const float* __restrict__ gamma, const float* __restrict__ beta,
    float invN, float* __restrict__ ss) {
  __shared__ float msum[54];
  __shared__ float m54[54];
  const int t = threadIdx.x;
  const int r = t >> 2, j = t & 3;
  if (r < 54) {
    const int chunk = NBLK >> 2;
    const float* row = p54 + (size_t)r * NBLK + j * chunk;
    float a0 = 0, a1 = 0, a2 = 0, a3 = 0, a4 = 0, a5 = 0, a6 = 0, a7 = 0;
    int b = 0;
    for (; b + 8 <= chunk; b += 8) {
      a0 += row[b];     a1 += row[b + 1]; a2 += row[b + 2]; a3 += row[b + 3];
      a4 += row[b + 4]; a5 += row[b + 5]; a6 += row[b + 6]; a7 += row[b + 7];
    }
    for (; b < chunk; ++b) a0 += row[b];
    float s = ((a0 + a1) + (a2 + a3)) + ((a4 + a5) + (a6 + a7));
    s += __shfl_xor(s, 1, 64);
    s += __shfl_xor(s, 2, 64);
    if (j == 0) msum[r] = s;
  }
  __syncthreads();
  // msum: [0..3]=Q1 [4..13]=Q2 [14..33]=S [34..38]=U1 [39..53]=U2
  if (t < 54) {
    float v;
    if (t < 9) {
      const int g2 = (t < 4) ? t : (t < 7 ? t - 4 : t - 7);
      v = msum[g2];
      if (t >= 4) v += msum[34 + (t - 4)];
    } else {
      int r2 = t - 9, c = 0;
      while (r2 >= 9 - c) { r2 -= 9 - c; ++c; }
      const int c2 = c + r2;
      const int a = (c < 4) ? c : (c < 7 ? c - 4 : c - 7);
      const int b2 = (c2 < 4) ? c2 : (c2 < 7 ? c2 - 4 : c2 - 7);
      const int lo = a < b2 ? a : b2, hi = a < b2 ? b2 : a;
      v = msum[4 + lo * (9 - lo) / 2 + (hi - lo)];  // 4x4 tri offsets 0/4/7/9
      if (c2 >= 4) v += msum[14 + a * 5 + (c2 - 4)];
      if (c >= 4) v += msum[14 + b2 * 5 + (c - 4)];
      if (c >= 4 && c2 >= 4) {
        const int ua = c - 4, ub = c2 - 4;  // ua <= ub
        v += msum[39 + ua * 5 - ua * (ua - 1) / 2 + (ub - ua)];
      }
    }
    m54[t] = v;
  }
  __syncthreads();
  if (t < 64) {
    float wc[9];
#pragma unroll
    for (int c = 0; c < 9; ++c) wc[c] = W[c * 64 + t];
    float mu = 0.f;
#pragma unroll
    for (int c = 0; c < 9; ++c) mu += m54[c] * invN * wc[c];
    float ex2 = 0.f;
    int idx = 9;
#pragma unroll
    for (int c = 0; c < 9; ++c)
#pragma unroll
      for (int c2 = c; c2 < 9; ++c2) {
        float v = m54[idx] * invN * wc[c] * wc[c2];
        ex2 += (c == c2) ? v : 2.f * v;
        ++idx;
      }
    const float var = ex2 - mu * mu;
    const float scale = gamma[t] * rsqrtf(var + 1e-3f);
    ss[t] = scale;
    ss[64 + t] = beta[t] - mu * scale;
  }
}

// ---------------- K3: bias + un-fold + BN + relu ----------------
__global__ void __launch_bounds__(256) pfn_apply(
    const float4* __restrict__ ext, const float4* __restrict__ rec,
    const int* __restrict__ coors, const float* __restrict__ W,
    const float* __restrict__ ss, int K, int P, float4* __restrict__ out) {
  const int t = blockIdx.x * 256 + threadIdx.x;
  if (t >= K * 16) return;
  const int k = t >> 4, j = t & 15;

  const float4* Wq = (const float4*)W;  // [9][16]
  const float4 v4 = Wq[4 * 16 + j], v5 = Wq[5 * 16 + j];
  const float4 v6 = Wq[6 * 16 + j], v7 = Wq[7 * 16 + j];
  const float4 v8 = Wq[8 * 16 + j];

  const float4 e = ext[t];
  const float4 rb = rec[2 * (size_t)k + 1];
  const float nvf = rb.w, inv = 1.f / nvf;
  const float cx = (float)coors[k * 4 + 3] * 0.2f + 0.1f;
  const float cy = (float)coors[k * 4 + 2] * 0.2f - 39.9f;
  const float o0 = -rb.x * inv, o1 = -rb.y * inv, o2 = -rb.z * inv;
  float4 bias;
  bias.x = v4.x * o0 + v5.x * o1 + v6.x * o2 - v7.x * cx - v8.x * cy;
  bias.y = v4.y * o0 + v5.y * o1 + v6.y * o2 - v7.y * cx - v8.y * cy;
  bias.z = v4.z * o0 + v5.z * o1 + v6.z * o2 - v7.z * cx - v8.z * cy;
  bias.w = v4.w * o0 + v5.w * o1 + v6.w * o2 - v7.w * cx - v8.w * cy;

  const float4 sc = ((const float4*)ss)[j];
  const float4 sh = ((const float4*)(ss + 64))[j];
  const bool masked = nvf < (float)P;

  float4 o;
  {
    const float sgn = (sc.x >= 0.f) ? 1.f : -1.f;
    float ev = sgn * e.x + bias.x;
    if (masked) ev = (sc.x >= 0.f) ? fmaxf(ev, 0.f) : fminf(ev, 0.f);
    o.x = fmaxf(fmaf(sc.x, ev, sh.x), 0.f);
  }
  {
    const float sgn = (sc.y >= 0.f) ? 1.f : -1.f;
    float ev = sgn * e.y + bias.y;
    if (masked) ev = (sc.y >= 0.f) ? fmaxf(ev, 0.f) : fminf(ev, 0.f);
    o.y = fmaxf(fmaf(sc.y, ev, sh.y), 0.f);
  }
  {
    const float sgn = (sc.z >= 0.f) ? 1.f : -1.f;
    float ev = sgn * e.z + bias.z;
    if (masked) ev = (sc.z >= 0.f) ? fmaxf(ev, 0.f) : fminf(ev, 0.f);
    o.z = fmaxf(fmaf(sc.z, ev, sh.z), 0.f);
  }
  {
    const float sgn = (sc.w >= 0.f) ? 1.f : -1.f;
    float ev = sgn * e.w + bias.w;
    if (masked) ev = (sc.w >= 0.f) ? fmaxf(ev, 0.f) : fminf(ev, 0.f);
    o.w = fmaxf(fmaf(sc.w, ev, sh.w), 0.f);
  }
  out[t] = o;
}

extern "C" void kernel_launch(void* const* d_in, const int* in_sizes, int n_in,
                              void* d_out, int out_size, void* d_ws,
                              size_t ws_size, hipStream_t stream) {
  const float4* feat = (const float4*)d_in[0];
  const int* nvox = (const int*)d_in[1];
  const int* coors = (const int*)d_in[2];
  const float* W = (const float*)d_in[3];
  const float* gamma = (const float*)d_in[4];
  const float* beta = (const float*)d_in[5];

  const int K = in_sizes[1];
  const int P = in_sizes[0] / (K * 4);

  // ws layout (floats): ss[128] | ext[K*16 f4] | rec[K*2 f4] | p54[54*NBLK]
  float* ss = (float*)d_ws;
  float4* ext = (float4*)(ss + 128);
  float4* rec = ext + (size_t)K * 16;
  float* p54 = (float*)(rec + (size_t)K * 2);

  const int nwaves = NBLK * 4;
  int cnt = (K + nwaves - 1) / nwaves;  // contiguous pillars per wave
  if (cnt > CMAX) cnt = CMAX;           // metadata hoist width (K<=20480 ok)

  pfn_main<<<NBLK, 256, 0, stream>>>(feat, nvox, coors, K, P, cnt, W, gamma,
                                     p54, ext, rec);
  pfn_finalize<<<1, 256, 0, stream>>>(p54, W, gamma, beta,
                                      1.0f / (float)((long long)K * P), ss);
  pfn_apply<<<(K * 16 + 255) / 256, 256, 0, stream>>>(ext, rec, coors, W, ss,
                                                      K, P, (float4*)d_out);
}

// Round 19
// 45.858 us; speedup vs baseline: 1.1477x; 1.0292x over previous
//
#include <hip/hip_runtime.h>

// PillarFeatureNet fused, 4 lean 256-thr kernels, R15 math verbatim:
//  K1a pfn_stats: wave per pillar run (no LDS, no weights): per-lane raw
//      second moments q2[10]; pure-DPP reductions + readlane(63) -> rec[k]
//      + lane-parallel cross-moments (single oacc). Partials p54[54][NBLK].
//  K1b pfn_ext: wave per pillar (weights + LDS only, NO serial chains):
//      channel-quad sign(gamma)-folded MAX extrema
//      (1 ds_read_b128 = 4 pts x 64 ch) -> ext.
//  K2  pfn_finalize: reduce p54 rows, assemble 54 augmented moments
//      (verified index maps), per-channel scale/shift -> ss.
//  K3  pfn_apply: bias from rec, un-fold by sign(scale), mask clamp, BN+relu.
// p54 rows: [0..3]=Q1 [4..13]=Q2 [14..33]=S [34..38]=U1 [39..53]=U2
// features [K,P,4] f32, num_voxels [K] i32, coors [K,4] i32,
// W [9,64] f32, gamma/beta [64] f32 -> out [K,64] f32.

#define NBLK 1280  // K1a blocks (divisible by 4 for K2 chunking)

// Pure-DPP wave sum; lane 63 holds the wave total. Zero DS ops.
__device__ __forceinline__ float wred63(float v) {
  int t;
  t = __builtin_amdgcn_update_dpp(0, __float_as_int(v), 0xB1, 0xf, 0xf, true);
  v += __int_as_float(t);  // quad_perm xor1
  t = __builtin_amdgcn_update_dpp(0, __float_as_int(v), 0x4E, 0xf, 0xf, true);
  v += __int_as_float(t);  // quad_perm xor2
  t = __builtin_amdgcn_update_dpp(0, __float_as_int(v), 0x141, 0xf, 0xf, true);
  v += __int_as_float(t);  // row_half_mirror = xor7
  t = __builtin_amdgcn_update_dpp(0, __float_as_int(v), 0x140, 0xf, 0xf, true);
  v += __int_as_float(t);  // row_mirror = xor15 -> row sums
  t = __builtin_amdgcn_update_dpp(0, __float_as_int(v), 0x142, 0xa, 0xf, true);
  v += __int_as_float(t);  // row_bcast15 -> rows 1,3
  t = __builtin_amdgcn_update_dpp(0, __float_as_int(v), 0x143, 0xc, 0xf, true);
  v += __int_as_float(t);  // row_bcast31 -> rows 2,3 (lane63 total)
  return v;
}
__device__ __forceinline__ float wsum_bcast(float v) {
  return __int_as_float(
      __builtin_amdgcn_readlane(__float_as_int(wred63(v)), 63));
}

// ---------------- K1a: stats only (no LDS, no weights) ----------------
__global__ void __launch_bounds__(256) pfn_stats(
    const float4* __restrict__ feat, const int* __restrict__ nvox,
    const int* __restrict__ coors, int K, int P, int cnt,
    float* __restrict__ p54, float4* __restrict__ rec) {
  __shared__ float red[4][56];
  const int lane = threadIdx.x & 63;
  const int wid = threadIdx.x >> 6;

  // ---- moment-row decode for this lane (constant) ----
  int sa = 0, sb = 0, ub = 0, ub2 = 0;
  if (lane >= 14 && lane < 34) { sa = (lane - 14) / 5; sb = (lane - 14) % 5; }
  if (lane >= 39 && lane < 54) {
    int r2 = lane - 39, b = 0;
    while (r2 >= 5 - b) { r2 -= 5 - b; ++b; }
    ub = b; ub2 = b + r2;
  }

  float q2[10] = {0, 0, 0, 0, 0, 0, 0, 0, 0, 0};
  float oacc = 0.f;

  const int gw = blockIdx.x * 4 + wid;
  const int k0 = gw * cnt;
  const int kend = (k0 + cnt < K) ? k0 + cnt : K;
  const bool hih = lane < (P - 64);  // P in (64,128]

  for (int k = k0; k < kend; ++k) {
    const size_t base = (size_t)k * P;
    const float4 f0 = feat[base + lane];
    float4 f1;
    if (hih) f1 = feat[base + 64 + lane];
    const int nv = nvox[k];

    // per-lane sums + raw second moments
    float sax = f0.x, say = f0.y, saz = f0.z;
    float svx = 0, svy = 0, svz = 0, svw = 0;
    if (lane < nv) {
      svx = f0.x; svy = f0.y; svz = f0.z; svw = f0.w;
      q2[0] = fmaf(f0.x, f0.x, q2[0]); q2[1] = fmaf(f0.x, f0.y, q2[1]);
      q2[2] = fmaf(f0.x, f0.z, q2[2]); q2[3] = fmaf(f0.x, f0.w, q2[3]);
      q2[4] = fmaf(f0.y, f0.y, q2[4]); q2[5] = fmaf(f0.y, f0.z, q2[5]);
      q2[6] = fmaf(f0.y, f0.w, q2[6]); q2[7] = fmaf(f0.z, f0.z, q2[7]);
      q2[8] = fmaf(f0.z, f0.w, q2[8]); q2[9] = fmaf(f0.w, f0.w, q2[9]);
    }
    if (hih) {
      sax += f1.x; say += f1.y; saz += f1.z;
      if (64 + lane < nv) {
        svx += f1.x; svy += f1.y; svz += f1.z; svw += f1.w;
        q2[0] = fmaf(f1.x, f1.x, q2[0]); q2[1] = fmaf(f1.x, f1.y, q2[1]);
        q2[2] = fmaf(f1.x, f1.z, q2[2]); q2[3] = fmaf(f1.x, f1.w, q2[3]);
        q2[4] = fmaf(f1.y, f1.y, q2[4]); q2[5] = fmaf(f1.y, f1.z, q2[5]);
        q2[6] = fmaf(f1.y, f1.w, q2[6]); q2[7] = fmaf(f1.z, f1.z, q2[7]);
        q2[8] = fmaf(f1.z, f1.w, q2[8]); q2[9] = fmaf(f1.w, f1.w, q2[9]);
      }
    }

    // 7 pure-DPP reductions -> uniform wave totals (zero DS ops)
    const float rx = wsum_bcast(sax);
    const float ry = wsum_bcast(say);
    const float rz = wsum_bcast(saz);
    const float vx = wsum_bcast(svx);
    const float vy = wsum_bcast(svy);
    const float vz = wsum_bcast(svz);
    const float vw = wsum_bcast(svw);

    const float nvf = (float)nv, inv = 1.f / nvf;
    const float cx = (float)coors[k * 4 + 3] * 0.2f + 0.1f;
    const float cy = (float)coors[k * 4 + 2] * 0.2f - 39.9f;
    const float o0 = -rx * inv, o1 = -ry * inv, o2 = -rz * inv;
    const float o3 = -cx, o4 = -cy;

    // lane-parallel cross-moment accumulation (1 register)
    {
      float add = 0.f;
      if (lane < 4) {
        add = (lane == 0) ? vx : (lane == 1) ? vy : (lane == 2) ? vz : vw;
      } else if (lane >= 14 && lane < 34) {
        const float sva = (sa == 0) ? vx : (sa == 1) ? vy : (sa == 2) ? vz : vw;
        const float ob = (sb == 0) ? o0 : (sb == 1) ? o1
                       : (sb == 2) ? o2 : (sb == 3) ? o3 : o4;
        add = sva * ob;
      } else if (lane >= 34 && lane < 39) {
        const int b = lane - 34;
        const float ob = (b == 0) ? o0 : (b == 1) ? o1
                       : (b == 2) ? o2 : (b == 3) ? o3 : o4;
        add = nvf * ob;
      } else if (lane >= 39 && lane < 54) {
        const float oa = (ub == 0) ? o0 : (ub == 1) ? o1
                       : (ub == 2) ? o2 : (ub == 3) ? o3 : o4;
        const float ob = (ub2 == 0) ? o0 : (ub2 == 1) ? o1
                       : (ub2 == 2) ? o2 : (ub2 == 3) ? o3 : o4;
        add = nvf * oa * ob;
      }
      oacc += add;
    }

    if (lane == 0) {
      float4 r0; r0.x = vx; r0.y = vy; r0.z = vz; r0.w = vw;
      float4 r1; r1.x = rx; r1.y = ry; r1.z = rz; r1.w = nvf;
      rec[2 * (size_t)k] = r0;
      rec[2 * (size_t)k + 1] = r1;
    }
  }

  // ---- block partials: rows 0..3,14..53 from oacc; 4..13 from q2 ----
  if (lane < 54 && (lane < 4 || lane >= 14)) red[wid][lane] = oacc;
#pragma unroll
  for (int i = 0; i < 10; ++i) q2[i] = wred63(q2[i]);
  if (lane == 63) {
#pragma unroll
    for (int i = 0; i < 10; ++i) red[wid][4 + i] = q2[i];
  }
  __syncthreads();
  const int t = threadIdx.x;
  if (t < 54) {
    p54[t * NBLK + blockIdx.x] =
        red[0][t] + red[1][t] + red[2][t] + red[3][t];
  }
}

// ---------------- K1b: extrema only (no serial chains) ----------------
__global__ void __launch_bounds__(256) pfn_ext(
    const float4* __restrict__ feat, const int* __restrict__ nvox, int K,
    int P, const float* __restrict__ W, const float* __restrict__ gamma,
    float4* __restrict__ ext) {
  __shared__ float4 pts[4][108];
  const int lane = threadIdx.x & 63;
  const int wid = threadIdx.x >> 6;
  const int q = lane & 15;  // channel quad (channels 4q..4q+3)
  const int g = lane >> 4;  // point group 0..3
  const int k = blockIdx.x * 4 + wid;
  if (k >= K) return;

  // ---- sign(gamma)-folded weight quads (sequential, low reg peak) ----
  const float4* Wq = (const float4*)W;  // [9][16]
  const float4 g4 = ((const float4*)gamma)[q];
  float4 sg;
  sg.x = (g4.x >= 0.f) ? 1.f : -1.f;
  sg.y = (g4.y >= 0.f) ? 1.f : -1.f;
  sg.z = (g4.z >= 0.f) ? 1.f : -1.f;
  sg.w = (g4.w >= 0.f) ? 1.f : -1.f;
  float4 wx, wy, wz, w3;
  {
    float4 t0 = Wq[0 * 16 + q], t1 = Wq[4 * 16 + q], t2 = Wq[7 * 16 + q];
    wx.x = (t0.x + t1.x + t2.x) * sg.x; wx.y = (t0.y + t1.y + t2.y) * sg.y;
    wx.z = (t0.z + t1.z + t2.z) * sg.z; wx.w = (t0.w + t1.w + t2.w) * sg.w;
  }
  {
    float4 t0 = Wq[1 * 16 + q], t1 = Wq[5 * 16 + q], t2 = Wq[8 * 16 + q];
    wy.x = (t0.x + t1.x + t2.x) * sg.x; wy.y = (t0.y + t1.y + t2.y) * sg.y;
    wy.z = (t0.z + t1.z + t2.z) * sg.z; wy.w = (t0.w + t1.w + t2.w) * sg.w;
  }
  {
    float4 t0 = Wq[2 * 16 + q], t1 = Wq[6 * 16 + q];
    wz.x = (t0.x + t1.x) * sg.x; wz.y = (t0.y + t1.y) * sg.y;
    wz.z = (t0.z + t1.z) * sg.z; wz.w = (t0.w + t1.w) * sg.w;
  }
  {
    float4 t0 = Wq[3 * 16 + q];
    w3.x = t0.x * sg.x; w3.y = t0.y * sg.y;
    w3.z = t0.z * sg.z; w3.w = t0.w * sg.w;
  }

  const size_t base = (size_t)k * P;
  pts[wid][lane] = feat[base + lane];
  if (lane < (P - 64)) pts[wid][64 + lane] = feat[base + 64 + lane];
  const int nv = nvox[k];

  // ---- channel-quad folded MAX extrema (verified R10 scheme) ----
  float4 m4 = {-3e38f, -3e38f, -3e38f, -3e38f};
  int p = 0;
  for (; p + 8 <= nv; p += 8) {
    const float4 fa = pts[wid][p + g];
    const float4 fb = pts[wid][p + 4 + g];
    m4.x = fmaxf(m4.x, fmaf(fa.x, wx.x, fmaf(fa.y, wy.x, fmaf(fa.z, wz.x, fa.w * w3.x))));
    m4.y = fmaxf(m4.y, fmaf(fa.x, wx.y, fmaf(fa.y, wy.y, fmaf(fa.z, wz.y, fa.w * w3.y))));
    m4.z = fmaxf(m4.z, fmaf(fa.x, wx.z, fmaf(fa.y, wy.z, fmaf(fa.z, wz.z, fa.w * w3.z))));
    m4.w = fmaxf(m4.w, fmaf(fa.x, wx.w, fmaf(fa.y, wy.w, fmaf(fa.z, wz.w, fa.w * w3.w))));
    m4.x = fmaxf(m4.x, fmaf(fb.x, wx.x, fmaf(fb.y, wy.x, fmaf(fb.z, wz.x, fb.w * w3.x))));
    m4.y = fmaxf(m4.y, fmaf(fb.x, wx.y, fmaf(fb.y, wy.y, fmaf(fb.z, wz.y, fb.w * w3.y))));
    m4.z = fmaxf(m4.z, fmaf(fb.x, wx.z, fmaf(fb.y, wy.z, fmaf(fb.z, wz.z, fb.w * w3.z))));
    m4.w = fmaxf(m4.w, fmaf(fb.x, wx.w, fmaf(fb.y, wy.w, fmaf(fb.z, wz.w, fb.w * w3.w))));
  }
  if (p < nv) {  // predicated tail octet
    const int i0 = p + g, i1 = p + 4 + g;
    const float4 fa = pts[wid][i0];
    const float4 fb = pts[wid][i1];
    if (i0 < nv) {
      m4.x = fmaxf(m4.x, fmaf(fa.x, wx.x, fmaf(fa.y, wy.x, fmaf(fa.z, wz.x, fa.w * w3.x))));
      m4.y = fmaxf(m4.y, fmaf(fa.x, wx.y, fmaf(fa.y, wy.y, fmaf(fa.z, wz.y, fa.w * w3.y))));
      m4.z = fmaxf(m4.z, fmaf(fa.x, wx.z, fmaf(fa.y, wy.z, fmaf(fa.z, wz.z, fa.w * w3.z))));
      m4.w = fmaxf(m4.w, fmaf(fa.x, wx.w, fmaf(fa.y, wy.w, fmaf(fa.z, wz.w, fa.w * w3.w))));
    }
    if (i1 < nv) {
      m4.x = fmaxf(m4.x, fmaf(fb.x, wx.x, fmaf(fb.y, wy.x, fmaf(fb.z, wz.x, fb.w * w3.x))));
      m4.y = fmaxf(m4.y, fmaf(fb.x, wx.y, fmaf(fb.y, wy.y, fmaf(fb.z, wz.y, fb.w * w3.y))));
      m4.z = fmaxf(m4.z, fmaf(fb.x, wx.z, fmaf(fb.y, wy.z, fmaf(fb.z, wz.z, fb.w * w3.z))));
      m4.w = fmaxf(m4.w, fmaf(fb.x, wx.w, fmaf(fb.y, wy.w, fmaf(fb.z, wz.w, fb.w * w3.w))));
    }
  }
  m4.x = fmaxf(m4.x, __shfl_xor(m4.x, 16, 64));
  m4.y = fmaxf(m4.y, __shfl_xor(m4.y, 16, 64));
  m4.z = fmaxf(m4.z, __shfl_xor(m4.z, 16, 64));
  m4.w = fmaxf(m4.w, __shfl_xor(m4.w, 16, 64));
  m4.x = fmaxf(m4.x, __shfl_xor(m4.x, 32, 64));
  m4.y = fmaxf(m4.y, __shfl_xor(m4.y, 32, 64));
  m4.z = fmaxf(m4.z, __shfl_xor(m4.z, 32, 64));
  m4.w = fmaxf(m4.w, __shfl_xor(m4.w, 32, 64));
  if (lane < 16) ext[(size_t)k * 16 + q] = m4;
}

// ---------------- K2: reduce + assemble + scale/shift ----------------
__global__ void __launch_bounds__(256) pfn_finalize(
    const float* __restrict__ p54, const float* __restrict__ W,
    const float* __restrict__ gamma, const float* __restrict__ beta,
    float invN, float* __restrict__ ss) {
  __shared__ float msum[54];
  __shared__ float m54[54];
  const int t = threadIdx.x;
  const int r = t >> 2, j = t & 3;
  if (r < 54) {
    const int chunk = NBLK >> 2;
    const float* row = p54 + (size_t)r * NBLK + j * chunk;
    float a0 = 0, a1 = 0, a2 = 0, a3 = 0, a4 = 0, a5 = 0, a6 = 0, a7 = 0;
    int b = 0;
    for (; b + 8 <= chunk; b += 8) {
      a0 += row[b];     a1 += row[b + 1]; a2 += row[b + 2]; a3 += row[b + 3];
      a4 += row[b + 4]; a5 += row[b + 5]; a6 += row[b + 6]; a7 += row[b + 7];
    }
    for (; b < chunk; ++b) a0 += row[b];
    float s = ((a0 + a1) + (a2 + a3)) + ((a4 + a5) + (a6 + a7));
    s += __shfl_xor(s, 1, 64);
    s += __shfl_xor(s, 2, 64);
    if (j == 0) msum[r] = s;
  }
  __syncthreads();
  // msum: [0..3]=Q1 [4..13]=Q2 [14..33]=S [34..38]=U1 [39..53]=U2
  if (t < 54) {
    float v;
    if (t < 9) {
      const int g2 = (t < 4) ? t : (t < 7 ? t - 4 : t - 7);
      v = msum[g2];
      if (t >= 4) v += msum[34 + (t - 4)];
    } else {
      int r2 = t - 9, c = 0;
      while (r2 >= 9 - c) { r2 -= 9 - c; ++c; }
      const int c2 = c + r2;
      const int a = (c < 4) ? c : (c < 7 ? c - 4 : c - 7);
      const int b2 = (c2 < 4) ? c2 : (c2 < 7 ? c2 - 4 : c2 - 7);
      const int lo = a < b2 ? a : b2, hi = a < b2 ? b2 : a;
      v = msum[4 + lo * (9 - lo) / 2 + (hi - lo)];  // 4x4 tri offsets 0/4/7/9
      if (c2 >= 4) v += msum[14 + a * 5 + (c2 - 4)];
      if (c >= 4) v += msum[14 + b2 * 5 + (c - 4)];
      if (c >= 4 && c2 >= 4) {
        const int ua = c - 4, ub = c2 - 4;  // ua <= ub
        v += msum[39 + ua * 5 - ua * (ua - 1) / 2 + (ub - ua)];
      }
    }
    m54[t] = v;
  }
  __syncthreads();
  if (t < 64) {
    float wc[9];
#pragma unroll
    for (int c = 0; c < 9; ++c) wc[c] = W[c * 64 + t];
    float mu = 0.f;
#pragma unroll
    for (int c = 0; c < 9; ++c) mu += m54[c] * invN * wc[c];
    float ex2 = 0.f;
    int idx = 9;
#pragma unroll
    for (int c = 0; c < 9; ++c)
#pragma unroll
      for (int c2 = c; c2 < 9; ++c2) {
        float v = m54[idx] * invN * wc[c] * wc[c2];
        ex2 += (c == c2) ? v : 2.f * v;
        ++idx;
      }
    const float var = ex2 - mu * mu;
    const float scale = gamma[t] * rsqrtf(var + 1e-3f);
    ss[t] = scale;
    ss[64 + t] = beta[t] - mu * scale;
  }
}

// ---------------- K3: bias + un-fold + BN + relu ----------------
__global__ void __launch_bounds__(256) pfn_apply(
    const float4* __restrict__ ext, const float4* __restrict__ rec,
    const int* __restrict__ coors, const float* __restrict__ W,
    const float* __restrict__ ss, int K, int P, float4* __restrict__ out) {
  const int t = blockIdx.x * 256 + threadIdx.x;
  if (t >= K * 16) return;
  const int k = t >> 4, j = t & 15;

  const float4* Wq = (const float4*)W;  // [9][16]
  const float4 v4 = Wq[4 * 16 + j], v5 = Wq[5 * 16 + j];
  const float4 v6 = Wq[6 * 16 + j], v7 = Wq[7 * 16 + j];
  const float4 v8 = Wq[8 * 16 + j];

  const float4 e = ext[t];
  const float4 rb = rec[2 * (size_t)k + 1];
  const float nvf = rb.w, inv = 1.f / nvf;
  const float cx = (float)coors[k * 4 + 3] * 0.2f + 0.1f;
  const float cy = (float)coors[k * 4 + 2] * 0.2f - 39.9f;
  const float o0 = -rb.x * inv, o1 = -rb.y * inv, o2 = -rb.z * inv;
  float4 bias;
  bias.x = v4.x * o0 + v5.x * o1 + v6.x * o2 - v7.x * cx - v8.x * cy;
  bias.y = v4.y * o0 + v5.y * o1 + v6.y * o2 - v7.y * cx - v8.y * cy;
  bias.z = v4.z * o0 + v5.z * o1 + v6.z * o2 - v7.z * cx - v8.z * cy;
  bias.w = v4.w * o0 + v5.w * o1 + v6.w * o2 - v7.w * cx - v8.w * cy;

  const float4 sc = ((const float4*)ss)[j];
  const float4 sh = ((const float4*)(ss + 64))[j];
  const bool masked = nvf < (float)P;

  float4 o;
  {
    const float sgn = (sc.x >= 0.f) ? 1.f : -1.f;
    float ev = sgn * e.x + bias.x;
    if (masked) ev = (sc.x >= 0.f) ? fmaxf(ev, 0.f) : fminf(ev, 0.f);
    o.x = fmaxf(fmaf(sc.x, ev, sh.x), 0.f);
  }
  {
    const float sgn = (sc.y >= 0.f) ? 1.f : -1.f;
    float ev = sgn * e.y + bias.y;
    if (masked) ev = (sc.y >= 0.f) ? fmaxf(ev, 0.f) : fminf(ev, 0.f);
    o.y = fmaxf(fmaf(sc.y, ev, sh.y), 0.f);
  }
  {
    const float sgn = (sc.z >= 0.f) ? 1.f : -1.f;
    float ev = sgn * e.z + bias.z;
    if (masked) ev = (sc.z >= 0.f) ? fmaxf(ev, 0.f) : fminf(ev, 0.f);
    o.z = fmaxf(fmaf(sc.z, ev, sh.z), 0.f);
  }
  {
    const float sgn = (sc.w >= 0.f) ? 1.f : -1.f;
    float ev = sgn * e.w + bias.w;
    if (masked) ev = (sc.w >= 0.f) ? fmaxf(ev, 0.f) : fminf(ev, 0.f);
    o.w = fmaxf(fmaf(sc.w, ev, sh.w), 0.f);
  }
  out[t] = o;
}

extern "C" void kernel_launch(void* const* d_in, const int* in_sizes, int n_in,
                              void* d_out, int out_size, void* d_ws,
                              size_t ws_size, hipStream_t stream) {
  const float4* feat = (const float4*)d_in[0];
  const int* nvox = (const int*)d_in[1];
  const int* coors = (const int*)d_in[2];
  const float* W = (const float*)d_in[3];
  const float* gamma = (const float*)d_in[4];
  const float* beta = (const float*)d_in[5];

  const int K = in_sizes[1];
  const int P = in_sizes[0] / (K * 4);

  // ws layout (floats): ss[128] | ext[K*16 f4] | rec[K*2 f4] | p54[54*NBLK]
  float* ss = (float*)d_ws;
  float4* ext = (float4*)(ss + 128);
  float4* rec = ext + (size_t)K * 16;
  float* p54 = (float*)(rec + (size_t)K * 2);

  const int nwaves = NBLK * 4;
  const int cnt = (K + nwaves - 1) / nwaves;  // contiguous pillars per wave

  pfn_stats<<<NBLK, 256, 0, stream>>>(feat, nvox, coors, K, P, cnt, p54, rec);
  pfn_ext<<<(K + 3) / 4, 256, 0, stream>>>(feat, nvox, K, P, W, gamma, ext);
  pfn_finalize<<<1, 256, 0, stream>>>(p54, W, gamma, beta,
                                      1.0f / (float)((long long)K * P), ss);
  pfn_apply<<<(K * 16 + 255) / 256, 256, 0, stream>>>(ext, rec, coors, W, ss,
                                                      K, P, (float4*)d_out);
}

// Round 20
// 42.755 us; speedup vs baseline: 1.2310x; 1.0726x over previous
//
#include <hip/hip_runtime.h>

// PillarFeatureNet fused, 3 kernels, single feature read, 256-thr blocks:
//  K1 pfn_main: wave per pillar (run of ~4): stage to LDS; per-lane raw
//     second moments q2[10]; pure-DPP reductions (wred63) + readlane(63)
//     SGPR broadcast (zero DS ops) -> rec[k] + lane-parallel cross-moments
//     in a single oacc register; channel-quad sign(gamma)-folded MAX
//     extrema (1 ds_read_b128 = 4 pts x 64 ch).
//     Block partials -> uniform p54[54][NBLK].
//  K2 pfn_finalize: reduce p54 rows, assemble 54 augmented moments
//     (verified index maps), per-channel scale/shift -> ss.
//  K3 pfn_apply: bias from rec, un-fold by sign(scale), mask clamp, BN+relu.
// p54 row layout: [0..3]=Q1 [4..13]=Q2 [14..33]=S [34..38]=U1 [39..53]=U2
// features [K,P,4] f32, num_voxels [K] i32, coors [K,4] i32,
// W [9,64] f32, gamma/beta [64] f32 -> out [K,64] f32.
//
// R20 = R15 verbatim (best measured: 42.8 us). Five structural variants
// (packed f32x2 math, forced 6 waves/SIMD, 2-way pillar ILP, prefetch +
// metadata hoist, stats/extrema kernel split) all regressed by 1-10 us;
// this configuration is the empirical optimum for this op shape.

#define NBLK 1280  // K1 blocks (divisible by 4 for K2 chunking)

// Pure-DPP wave sum: butterfly in row16, then row_bcast15/31 cascade.
// Lane 63 holds the wave total. 6 VALU ops, zero DS ops.
__device__ __forceinline__ float wred63(float v) {
  int t;
  t = __builtin_amdgcn_update_dpp(0, __float_as_int(v), 0xB1, 0xf, 0xf, true);
  v += __int_as_float(t);  // quad_perm xor1
  t = __builtin_amdgcn_update_dpp(0, __float_as_int(v), 0x4E, 0xf, 0xf, true);
  v += __int_as_float(t);  // quad_perm xor2
  t = __builtin_amdgcn_update_dpp(0, __float_as_int(v), 0x141, 0xf, 0xf, true);
  v += __int_as_float(t);  // row_half_mirror = xor7
  t = __builtin_amdgcn_update_dpp(0, __float_as_int(v), 0x140, 0xf, 0xf, true);
  v += __int_as_float(t);  // row_mirror = xor15 -> row sums
  t = __builtin_amdgcn_update_dpp(0, __float_as_int(v), 0x142, 0xa, 0xf, true);
  v += __int_as_float(t);  // row_bcast15 -> rows 1,3
  t = __builtin_amdgcn_update_dpp(0, __float_as_int(v), 0x143, 0xc, 0xf, true);
  v += __int_as_float(t);  // row_bcast31 -> rows 2,3 (lane63 total)
  return v;
}
// Wave total broadcast to all lanes as a uniform (SGPR) value. No DS ops.
__device__ __forceinline__ float wsum_bcast(float v) {
  return __int_as_float(
      __builtin_amdgcn_readlane(__float_as_int(wred63(v)), 63));
}

// ---------------- K1 ----------------
__global__ void __launch_bounds__(256) pfn_main(
    const float4* __restrict__ feat, const int* __restrict__ nvox,
    const int* __restrict__ coors, int K, int P, int cnt,
    const float* __restrict__ W, const float* __restrict__ gamma,
    float* __restrict__ p54, float4* __restrict__ ext,
    float4* __restrict__ rec) {
  __shared__ float4 pts[4][108];
  __shared__ float red[4][56];
  const int lane = threadIdx.x & 63;
  const int wid = threadIdx.x >> 6;
  const int q = lane & 15;  // channel quad (channels 4q..4q+3)
  const int g = lane >> 4;  // point group 0..3

  // ---- moment-row decode for this lane (constant) ----
  int sa = 0, sb = 0, ub = 0, ub2 = 0;
  if (lane >= 14 && lane < 34) { sa = (lane - 14) / 5; sb = (lane - 14) % 5; }
  if (lane >= 39 && lane < 54) {
    int r2 = lane - 39, b = 0;
    while (r2 >= 5 - b) { r2 -= 5 - b; ++b; }
    ub = b; ub2 = b + r2;
  }

  // ---- sign(gamma)-folded weight quads (sequential, low reg peak) ----
  const float4* Wq = (const float4*)W;  // [9][16]
  const float4 g4 = ((const float4*)gamma)[q];
  float4 sg;
  sg.x = (g4.x >= 0.f) ? 1.f : -1.f;
  sg.y = (g4.y >= 0.f) ? 1.f : -1.f;
  sg.z = (g4.z >= 0.f) ? 1.f : -1.f;
  sg.w = (g4.w >= 0.f) ? 1.f : -1.f;
  float4 wx, wy, wz, w3;
  {
    float4 t0 = Wq[0 * 16 + q], t1 = Wq[4 * 16 + q], t2 = Wq[7 * 16 + q];
    wx.x = (t0.x + t1.x + t2.x) * sg.x; wx.y = (t0.y + t1.y + t2.y) * sg.y;
    wx.z = (t0.z + t1.z + t2.z) * sg.z; wx.w = (t0.w + t1.w + t2.w) * sg.w;
  }
  {
    float4 t0 = Wq[1 * 16 + q], t1 = Wq[5 * 16 + q], t2 = Wq[8 * 16 + q];
    wy.x = (t0.x + t1.x + t2.x) * sg.x; wy.y = (t0.y + t1.y + t2.y) * sg.y;
    wy.z = (t0.z + t1.z + t2.z) * sg.z; wy.w = (t0.w + t1.w + t2.w) * sg.w;
  }
  {
    float4 t0 = Wq[2 * 16 + q], t1 = Wq[6 * 16 + q];
    wz.x = (t0.x + t1.x) * sg.x; wz.y = (t0.y + t1.y) * sg.y;
    wz.z = (t0.z + t1.z) * sg.z; wz.w = (t0.w + t1.w) * sg.w;
  }
  {
    float4 t0 = Wq[3 * 16 + q];
    w3.x = t0.x * sg.x; w3.y = t0.y * sg.y;
    w3.z = t0.z * sg.z; w3.w = t0.w * sg.w;
  }

  float q2[10] = {0, 0, 0, 0, 0, 0, 0, 0, 0, 0};
  float oacc = 0.f;

  const int gw = blockIdx.x * 4 + wid;
  const int k0 = gw * cnt;
  const int kend = (k0 + cnt < K) ? k0 + cnt : K;
  const bool hih = lane < (P - 64);  // P in (64,128]

  for (int k = k0; k < kend; ++k) {
    const size_t base = (size_t)k * P;
    const float4 f0 = feat[base + lane];
    float4 f1;
    if (hih) f1 = feat[base + 64 + lane];
    const int nv = nvox[k];

    // stage (single buffer; wave-private row, same-wave ordering safe)
    pts[wid][lane] = f0;
    if (hih) pts[wid][64 + lane] = f1;

    // per-lane sums + raw second moments
    float sax = f0.x, say = f0.y, saz = f0.z;
    float svx = 0, svy = 0, svz = 0, svw = 0;
    if (lane < nv) {
      svx = f0.x; svy = f0.y; svz = f0.z; svw = f0.w;
      q2[0] = fmaf(f0.x, f0.x, q2[0]); q2[1] = fmaf(f0.x, f0.y, q2[1]);
      q2[2] = fmaf(f0.x, f0.z, q2[2]); q2[3] = fmaf(f0.x, f0.w, q2[3]);
      q2[4] = fmaf(f0.y, f0.y, q2[4]); q2[5] = fmaf(f0.y, f0.z, q2[5]);
      q2[6] = fmaf(f0.y, f0.w, q2[6]); q2[7] = fmaf(f0.z, f0.z, q2[7]);
      q2[8] = fmaf(f0.z, f0.w, q2[8]); q2[9] = fmaf(f0.w, f0.w, q2[9]);
    }
    if (hih) {
      sax += f1.x; say += f1.y; saz += f1.z;
      if (64 + lane < nv) {
        svx += f1.x; svy += f1.y; svz += f1.z; svw += f1.w;
        q2[0] = fmaf(f1.x, f1.x, q2[0]); q2[1] = fmaf(f1.x, f1.y, q2[1]);
        q2[2] = fmaf(f1.x, f1.z, q2[2]); q2[3] = fmaf(f1.x, f1.w, q2[3]);
        q2[4] = fmaf(f1.y, f1.y, q2[4]); q2[5] = fmaf(f1.y, f1.z, q2[5]);
        q2[6] = fmaf(f1.y, f1.w, q2[6]); q2[7] = fmaf(f1.z, f1.z, q2[7]);
        q2[8] = fmaf(f1.z, f1.w, q2[8]); q2[9] = fmaf(f1.w, f1.w, q2[9]);
      }
    }

    // 7 pure-DPP reductions -> uniform (SGPR) wave totals. Zero DS ops.
    const float rx = wsum_bcast(sax);
    const float ry = wsum_bcast(say);
    const float rz = wsum_bcast(saz);
    const float vx = wsum_bcast(svx);
    const float vy = wsum_bcast(svy);
    const float vz = wsum_bcast(svz);
    const float vw = wsum_bcast(svw);

    const float nvf = (float)nv, inv = 1.f / nvf;
    const float cx = (float)coors[k * 4 + 3] * 0.2f + 0.1f;
    const float cy = (float)coors[k * 4 + 2] * 0.2f - 39.9f;
    const float o0 = -rx * inv, o1 = -ry * inv, o2 = -rz * inv;
    const float o3 = -cx, o4 = -cy;

    // lane-parallel cross-moment accumulation (1 register)
    {
      float add = 0.f;
      if (lane < 4) {
        add = (lane == 0) ? vx : (lane == 1) ? vy : (lane == 2) ? vz : vw;
      } else if (lane >= 14 && lane < 34) {
        const float sva = (sa == 0) ? vx : (sa == 1) ? vy : (sa == 2) ? vz : vw;
        const float ob = (sb == 0) ? o0 : (sb == 1) ? o1
                       : (sb == 2) ? o2 : (sb == 3) ? o3 : o4;
        add = sva * ob;
      } else if (lane >= 34 && lane < 39) {
        const int b = lane - 34;
        const float ob = (b == 0) ? o0 : (b == 1) ? o1
                       : (b == 2) ? o2 : (b == 3) ? o3 : o4;
        add = nvf * ob;
      } else if (lane >= 39 && lane < 54) {
        const float oa = (ub == 0) ? o0 : (ub == 1) ? o1
                       : (ub == 2) ? o2 : (ub == 3) ? o3 : o4;
        const float ob = (ub2 == 0) ? o0 : (ub2 == 1) ? o1
                       : (ub2 == 2) ? o2 : (ub2 == 3) ? o3 : o4;
        add = nvf * oa * ob;
      }
      oacc += add;
    }

    if (lane == 0) {
      float4 r0; r0.x = vx; r0.y = vy; r0.z = vz; r0.w = vw;
      float4 r1; r1.x = rx; r1.y = ry; r1.z = rz; r1.w = nvf;
      rec[2 * (size_t)k] = r0;
      rec[2 * (size_t)k + 1] = r1;
    }

    // channel-quad folded MAX extrema (verified R10 scheme)
    float4 m4 = {-3e38f, -3e38f, -3e38f, -3e38f};
    int p = 0;
    for (; p + 8 <= nv; p += 8) {
      const float4 fa = pts[wid][p + g];
      const float4 fb = pts[wid][p + 4 + g];
      m4.x = fmaxf(m4.x, fmaf(fa.x, wx.x, fmaf(fa.y, wy.x, fmaf(fa.z, wz.x, fa.w * w3.x))));
      m4.y = fmaxf(m4.y, fmaf(fa.x, wx.y, fmaf(fa.y, wy.y, fmaf(fa.z, wz.y, fa.w * w3.y))));
      m4.z = fmaxf(m4.z, fmaf(fa.x, wx.z, fmaf(fa.y, wy.z, fmaf(fa.z, wz.z, fa.w * w3.z))));
      m4.w = fmaxf(m4.w, fmaf(fa.x, wx.w, fmaf(fa.y, wy.w, fmaf(fa.z, wz.w, fa.w * w3.w))));
      m4.x = fmaxf(m4.x, fmaf(fb.x, wx.x, fmaf(fb.y, wy.x, fmaf(fb.z, wz.x, fb.w * w3.x))));
      m4.y = fmaxf(m4.y, fmaf(fb.x, wx.y, fmaf(fb.y, wy.y, fmaf(fb.z, wz.y, fb.w * w3.y))));
      m4.z = fmaxf(m4.z, fmaf(fb.x, wx.z, fmaf(fb.y, wy.z, fmaf(fb.z, wz.z, fb.w * w3.z))));
      m4.w = fmaxf(m4.w, fmaf(fb.x, wx.w, fmaf(fb.y, wy.w, fmaf(fb.z, wz.w, fb.w * w3.w))));
    }
    if (p < nv) {  // predicated tail octet
      const int i0 = p + g, i1 = p + 4 + g;
      const float4 fa = pts[wid][i0];
      const float4 fb = pts[wid][i1];
      if (i0 < nv) {
        m4.x = fmaxf(m4.x, fmaf(fa.x, wx.x, fmaf(fa.y, wy.x, fmaf(fa.z, wz.x, fa.w * w3.x))));
        m4.y = fmaxf(m4.y, fmaf(fa.x, wx.y, fmaf(fa.y, wy.y, fmaf(fa.z, wz.y, fa.w * w3.y))));
        m4.z = fmaxf(m4.z, fmaf(fa.x, wx.z, fmaf(fa.y, wy.z, fmaf(fa.z, wz.z, fa.w * w3.z))));
        m4.w = fmaxf(m4.w, fmaf(fa.x, wx.w, fmaf(fa.y, wy.w, fmaf(fa.z, wz.w, fa.w * w3.w))));
      }
      if (i1 < nv) {
        m4.x = fmaxf(m4.x, fmaf(fb.x, wx.x, fmaf(fb.y, wy.x, fmaf(fb.z, wz.x, fb.w * w3.x))));
        m4.y = fmaxf(m4.y, fmaf(fb.x, wx.y, fmaf(fb.y, wy.y, fmaf(fb.z, wz.y, fb.w * w3.y))));
        m4.z = fmaxf(m4.z, fmaf(fb.x, wx.z, fmaf(fb.y, wy.z, fmaf(fb.z, wz.z, fb.w * w3.z))));
        m4.w = fmaxf(m4.w, fmaf(fb.x, wx.w, fmaf(fb.y, wy.w, fmaf(fb.z, wz.w, fb.w * w3.w))));
      }
    }
    m4.x = fmaxf(m4.x, __shfl_xor(m4.x, 16, 64));
    m4.y = fmaxf(m4.y, __shfl_xor(m4.y, 16, 64));
    m4.z = fmaxf(m4.z, __shfl_xor(m4.z, 16, 64));
    m4.w = fmaxf(m4.w, __shfl_xor(m4.w, 16, 64));
    m4.x = fmaxf(m4.x, __shfl_xor(m4.x, 32, 64));
    m4.y = fmaxf(m4.y, __shfl_xor(m4.y, 32, 64));
    m4.z = fmaxf(m4.z, __shfl_xor(m4.z, 32, 64));
    m4.w = fmaxf(m4.w, __shfl_xor(m4.w, 32, 64));
    if (lane < 16) ext[(size_t)k * 16 + q] = m4;
  }

  // ---- block partials: rows 0..3,14..53 from oacc; 4..13 from q2 ----
  if (lane < 54 && (lane < 4 || lane >= 14)) red[wid][lane] = oacc;
#pragma unroll
  for (int i = 0; i < 10; ++i) q2[i] = wred63(q2[i]);
  if (lane == 63) {
#pragma unroll
    for (int i = 0; i < 10; ++i) red[wid][4 + i] = q2[i];
  }
  __syncthreads();
  const int t = threadIdx.x;
  if (t < 54) {
    p54[t * NBLK + blockIdx.x] =
        red[0][t] + red[1][t] + red[2][t] + red[3][t];
  }
}

// ---------------- K2: reduce + assemble + scale/shift ----------------
__global__ void __launch_bounds__(256) pfn_finalize(
    const float* __restrict__ p54, const float* __restrict__ W,
    const float* __restrict__ gamma, const float* __restrict__ beta,
    float invN, float* __restrict__ ss) {
  __shared__ float msum[54];
  __shared__ float m54[54];
  const int t = threadIdx.x;
  const int r = t >> 2, j = t & 3;
  if (r < 54) {
    const int chunk = NBLK >> 2;
    const float* row = p54 + (size_t)r * NBLK + j * chunk;
    float a0 = 0, a1 = 0, a2 = 0, a3 = 0, a4 = 0, a5 = 0, a6 = 0, a7 = 0;
    int b = 0;
    for (; b + 8 <= chunk; b += 8) {
      a0 += row[b];     a1 += row[b + 1]; a2 += row[b + 2]; a3 += row[b + 3];
      a4 += row[b + 4]; a5 += row[b + 5]; a6 += row[b + 6]; a7 += row[b + 7];
    }
    for (; b < chunk; ++b) a0 += row[b];
    float s = ((a0 + a1) + (a2 + a3)) + ((a4 + a5) + (a6 + a7));
    s += __shfl_xor(s, 1, 64);
    s += __shfl_xor(s, 2, 64);
    if (j == 0) msum[r] = s;
  }
  __syncthreads();
  // msum: [0..3]=Q1 [4..13]=Q2 [14..33]=S [34..38]=U1 [39..53]=U2
  if (t < 54) {
    float v;
    if (t < 9) {
      const int g2 = (t < 4) ? t : (t < 7 ? t - 4 : t - 7);
      v = msum[g2];
      if (t >= 4) v += msum[34 + (t - 4)];
    } else {
      int r2 = t - 9, c = 0;
      while (r2 >= 9 - c) { r2 -= 9 - c; ++c; }
      const int c2 = c + r2;
      const int a = (c < 4) ? c : (c < 7 ? c - 4 : c - 7);
      const int b2 = (c2 < 4) ? c2 : (c2 < 7 ? c2 - 4 : c2 - 7);
      const int lo = a < b2 ? a : b2, hi = a < b2 ? b2 : a;
      v = msum[4 + lo * (9 - lo) / 2 + (hi - lo)];  // 4x4 tri offsets 0/4/7/9
      if (c2 >= 4) v += msum[14 + a * 5 + (c2 - 4)];
      if (c >= 4) v += msum[14 + b2 * 5 + (c - 4)];
      if (c >= 4 && c2 >= 4) {
        const int ua = c - 4, ub = c2 - 4;  // ua <= ub
        v += msum[39 + ua * 5 - ua * (ua - 1) / 2 + (ub - ua)];
      }
    }
    m54[t] = v;
  }
  __syncthreads();
  if (t < 64) {
    float wc[9];
#pragma unroll
    for (int c = 0; c < 9; ++c) wc[c] = W[c * 64 + t];
    float mu = 0.f;
#pragma unroll
    for (int c = 0; c < 9; ++c) mu += m54[c] * invN * wc[c];
    float ex2 = 0.f;
    int idx = 9;
#pragma unroll
    for (int c = 0; c < 9; ++c)
#pragma unroll
      for (int c2 = c; c2 < 9; ++c2) {
        float v = m54[idx] * invN * wc[c] * wc[c2];
        ex2 += (c == c2) ? v : 2.f * v;
        ++idx;
      }
    const float var = ex2 - mu * mu;
    const float scale = gamma[t] * rsqrtf(var + 1e-3f);
    ss[t] = scale;
    ss[64 + t] = beta[t] - mu * scale;
  }
}

// ---------------- K3: bias + un-fold + BN + relu ----------------
__global__ void __launch_bounds__(256) pfn_apply(
    const float4* __restrict__ ext, const float4* __restrict__ rec,
    const int* __restrict__ coors, const float* __restrict__ W,
    const float* __restrict__ ss, int K, int P, float4* __restrict__ out) {
  const int t = blockIdx.x * 256 + threadIdx.x;
  if (t >= K * 16) return;
  const int k = t >> 4, j = t & 15;

  const float4* Wq = (const float4*)W;  // [9][16]
  const float4 v4 = Wq[4 * 16 + j], v5 = Wq[5 * 16 + j];
  const float4 v6 = Wq[6 * 16 + j], v7 = Wq[7 * 16 + j];
  const float4 v8 = Wq[8 * 16 + j];

  const float4 e = ext[t];
  const float4 rb = rec[2 * (size_t)k + 1];
  const float nvf = rb.w, inv = 1.f / nvf;
  const float cx = (float)coors[k * 4 + 3] * 0.2f + 0.1f;
  const float cy = (float)coors[k * 4 + 2] * 0.2f - 39.9f;
  const float o0 = -rb.x * inv, o1 = -rb.y * inv, o2 = -rb.z * inv;
  float4 bias;
  bias.x = v4.x * o0 + v5.x * o1 + v6.x * o2 - v7.x * cx - v8.x * cy;
  bias.y = v4.y * o0 + v5.y * o1 + v6.y * o2 - v7.y * cx - v8.y * cy;
  bias.z = v4.z * o0 + v5.z * o1 + v6.z * o2 - v7.z * cx - v8.z * cy;
  bias.w = v4.w * o0 + v5.w * o1 + v6.w * o2 - v7.w * cx - v8.w * cy;

  const float4 sc = ((const float4*)ss)[j];
  const float4 sh = ((const float4*)(ss + 64))[j];
  const bool masked = nvf < (float)P;

  float4 o;
  {
    const float sgn = (sc.x >= 0.f) ? 1.f : -1.f;
    float ev = sgn * e.x + bias.x;
    if (masked) ev = (sc.x >= 0.f) ? fmaxf(ev, 0.f) : fminf(ev, 0.f);
    o.x = fmaxf(fmaf(sc.x, ev, sh.x), 0.f);
  }
  {
    const float sgn = (sc.y >= 0.f) ? 1.f : -1.f;
    float ev = sgn * e.y + bias.y;
    if (masked) ev = (sc.y >= 0.f) ? fmaxf(ev, 0.f) : fminf(ev, 0.f);
    o.y = fmaxf(fmaf(sc.y, ev, sh.y), 0.f);
  }
  {
    const float sgn = (sc.z >= 0.f) ? 1.f : -1.f;
    float ev = sgn * e.z + bias.z;
    if (masked) ev = (sc.z >= 0.f) ? fmaxf(ev, 0.f) : fminf(ev, 0.f);
    o.z = fmaxf(fmaf(sc.z, ev, sh.z), 0.f);
  }
  {
    const float sgn = (sc.w >= 0.f) ? 1.f : -1.f;
    float ev = sgn * e.w + bias.w;
    if (masked) ev = (sc.w >= 0.f) ? fmaxf(ev, 0.f) : fminf(ev, 0.f);
    o.w = fmaxf(fmaf(sc.w, ev, sh.w), 0.f);
  }
  out[t] = o;
}

extern "C" void kernel_launch(void* const* d_in, const int* in_sizes, int n_in,
                              void* d_out, int out_size, void* d_ws,
                              size_t ws_size, hipStream_t stream) {
  const float4* feat = (const float4*)d_in[0];
  const int* nvox = (const int*)d_in[1];
  const int* coors = (const int*)d_in[2];
  const float* W = (const float*)d_in[3];
  const float* gamma = (const float*)d_in[4];
  const float* beta = (const float*)d_in[5];

  const int K = in_sizes[1];
  const int P = in_sizes[0] / (K * 4);

  // ws layout (floats): ss[128] | ext[K*16 f4] | rec[K*2 f4] | p54[54*NBLK]
  float* ss = (float*)d_ws;
  float4* ext = (float4*)(ss + 128);
  float4* rec = ext + (size_t)K * 16;
  float* p54 = (float*)(rec + (size_t)K * 2);

  const int nwaves = NBLK * 4;
  const int cnt = (K + nwaves - 1) / nwaves;  // contiguous pillars per wave

  pfn_main<<<NBLK, 256, 0, stream>>>(feat, nvox, coors, K, P, cnt, W, gamma,
                                     p54, ext, rec);
  pfn_finalize<<<1, 256, 0, stream>>>(p54, W, gamma, beta,
                                      1.0f / (float)((long long)K * P), ss);
  pfn_apply<<<(K * 16 + 255) / 256, 256, 0, stream>>>(ext, rec, coors, W, ss,
                                                      K, P, (float4*)d_out);
}

// Round 21
// 40.819 us; speedup vs baseline: 1.2894x; 1.0474x over previous
//
#include <hip/hip_runtime.h>

// PillarFeatureNet fused, 3 kernels, single feature read, 256-thr blocks.
// R21 = R20 (= R15, best 42.8us) with ONE isolated change: K2 finalize
// widened to 1024 threads (16 readers/row, chunk 80) to cut its serial
// partial-reduction latency (~8us -> ~2us if it was the hidden term).
//  K1 pfn_main: wave per pillar (run of ~4): stage to LDS; per-lane raw
//     second moments q2[10]; pure-DPP reductions (wred63) + readlane(63)
//     SGPR broadcast (zero DS ops) -> rec[k] + lane-parallel cross-moments
//     in a single oacc register; channel-quad sign(gamma)-folded MAX
//     extrema (1 ds_read_b128 = 4 pts x 64 ch).
//     Block partials -> uniform p54[54][NBLK].
//  K2 pfn_finalize (1024 thr): reduce p54 rows, assemble 54 augmented
//     moments (verified index maps), per-channel scale/shift -> ss.
//  K3 pfn_apply: bias from rec, un-fold by sign(scale), mask clamp, BN+relu.
// p54 row layout: [0..3]=Q1 [4..13]=Q2 [14..33]=S [34..38]=U1 [39..53]=U2
// features [K,P,4] f32, num_voxels [K] i32, coors [K,4] i32,
// W [9,64] f32, gamma/beta [64] f32 -> out [K,64] f32.

#define NBLK 1280  // K1 blocks (divisible by 16 for K2 chunking)

// Pure-DPP wave sum: butterfly in row16, then row_bcast15/31 cascade.
// Lane 63 holds the wave total. 6 VALU ops, zero DS ops.
__device__ __forceinline__ float wred63(float v) {
  int t;
  t = __builtin_amdgcn_update_dpp(0, __float_as_int(v), 0xB1, 0xf, 0xf, true);
  v += __int_as_float(t);  // quad_perm xor1
  t = __builtin_amdgcn_update_dpp(0, __float_as_int(v), 0x4E, 0xf, 0xf, true);
  v += __int_as_float(t);  // quad_perm xor2
  t = __builtin_amdgcn_update_dpp(0, __float_as_int(v), 0x141, 0xf, 0xf, true);
  v += __int_as_float(t);  // row_half_mirror = xor7
  t = __builtin_amdgcn_update_dpp(0, __float_as_int(v), 0x140, 0xf, 0xf, true);
  v += __int_as_float(t);  // row_mirror = xor15 -> row sums
  t = __builtin_amdgcn_update_dpp(0, __float_as_int(v), 0x142, 0xa, 0xf, true);
  v += __int_as_float(t);  // row_bcast15 -> rows 1,3
  t = __builtin_amdgcn_update_dpp(0, __float_as_int(v), 0x143, 0xc, 0xf, true);
  v += __int_as_float(t);  // row_bcast31 -> rows 2,3 (lane63 total)
  return v;
}
// Wave total broadcast to all lanes as a uniform (SGPR) value. No DS ops.
__device__ __forceinline__ float wsum_bcast(float v) {
  return __int_as_float(
      __builtin_amdgcn_readlane(__float_as_int(wred63(v)), 63));
}

// ---------------- K1 ----------------
__global__ void __launch_bounds__(256) pfn_main(
    const float4* __restrict__ feat, const int* __restrict__ nvox,
    const int* __restrict__ coors, int K, int P, int cnt,
    const float* __restrict__ W, const float* __restrict__ gamma,
    float* __restrict__ p54, float4* __restrict__ ext,
    float4* __restrict__ rec) {
  __shared__ float4 pts[4][108];
  __shared__ float red[4][56];
  const int lane = threadIdx.x & 63;
  const int wid = threadIdx.x >> 6;
  const int q = lane & 15;  // channel quad (channels 4q..4q+3)
  const int g = lane >> 4;  // point group 0..3

  // ---- moment-row decode for this lane (constant) ----
  int sa = 0, sb = 0, ub = 0, ub2 = 0;
  if (lane >= 14 && lane < 34) { sa = (lane - 14) / 5; sb = (lane - 14) % 5; }
  if (lane >= 39 && lane < 54) {
    int r2 = lane - 39, b = 0;
    while (r2 >= 5 - b) { r2 -= 5 - b; ++b; }
    ub = b; ub2 = b + r2;
  }

  // ---- sign(gamma)-folded weight quads (sequential, low reg peak) ----
  const float4* Wq = (const float4*)W;  // [9][16]
  const float4 g4 = ((const float4*)gamma)[q];
  float4 sg;
  sg.x = (g4.x >= 0.f) ? 1.f : -1.f;
  sg.y = (g4.y >= 0.f) ? 1.f : -1.f;
  sg.z = (g4.z >= 0.f) ? 1.f : -1.f;
  sg.w = (g4.w >= 0.f) ? 1.f : -1.f;
  float4 wx, wy, wz, w3;
  {
    float4 t0 = Wq[0 * 16 + q], t1 = Wq[4 * 16 + q], t2 = Wq[7 * 16 + q];
    wx.x = (t0.x + t1.x + t2.x) * sg.x; wx.y = (t0.y + t1.y + t2.y) * sg.y;
    wx.z = (t0.z + t1.z + t2.z) * sg.z; wx.w = (t0.w + t1.w + t2.w) * sg.w;
  }
  {
    float4 t0 = Wq[1 * 16 + q], t1 = Wq[5 * 16 + q], t2 = Wq[8 * 16 + q];
    wy.x = (t0.x + t1.x + t2.x) * sg.x; wy.y = (t0.y + t1.y + t2.y) * sg.y;
    wy.z = (t0.z + t1.z + t2.z) * sg.z; wy.w = (t0.w + t1.w + t2.w) * sg.w;
  }
  {
    float4 t0 = Wq[2 * 16 + q], t1 = Wq[6 * 16 + q];
    wz.x = (t0.x + t1.x) * sg.x; wz.y = (t0.y + t1.y) * sg.y;
    wz.z = (t0.z + t1.z) * sg.z; wz.w = (t0.w + t1.w) * sg.w;
  }
  {
    float4 t0 = Wq[3 * 16 + q];
    w3.x = t0.x * sg.x; w3.y = t0.y * sg.y;
    w3.z = t0.z * sg.z; w3.w = t0.w * sg.w;
  }

  float q2[10] = {0, 0, 0, 0, 0, 0, 0, 0, 0, 0};
  float oacc = 0.f;

  const int gw = blockIdx.x * 4 + wid;
  const int k0 = gw * cnt;
  const int kend = (k0 + cnt < K) ? k0 + cnt : K;
  const bool hih = lane < (P - 64);  // P in (64,128]

  for (int k = k0; k < kend; ++k) {
    const size_t base = (size_t)k * P;
    const float4 f0 = feat[base + lane];
    float4 f1;
    if (hih) f1 = feat[base + 64 + lane];
    const int nv = nvox[k];

    // stage (single buffer; wave-private row, same-wave ordering safe)
    pts[wid][lane] = f0;
    if (hih) pts[wid][64 + lane] = f1;

    // per-lane sums + raw second moments
    float sax = f0.x, say = f0.y, saz = f0.z;
    float svx = 0, svy = 0, svz = 0, svw = 0;
    if (lane < nv) {
      svx = f0.x; svy = f0.y; svz = f0.z; svw = f0.w;
      q2[0] = fmaf(f0.x, f0.x, q2[0]); q2[1] = fmaf(f0.x, f0.y, q2[1]);
      q2[2] = fmaf(f0.x, f0.z, q2[2]); q2[3] = fmaf(f0.x, f0.w, q2[3]);
      q2[4] = fmaf(f0.y, f0.y, q2[4]); q2[5] = fmaf(f0.y, f0.z, q2[5]);
      q2[6] = fmaf(f0.y, f0.w, q2[6]); q2[7] = fmaf(f0.z, f0.z, q2[7]);
      q2[8] = fmaf(f0.z, f0.w, q2[8]); q2[9] = fmaf(f0.w, f0.w, q2[9]);
    }
    if (hih) {
      sax += f1.x; say += f1.y; saz += f1.z;
      if (64 + lane < nv) {
        svx += f1.x; svy += f1.y; svz += f1.z; svw += f1.w;
        q2[0] = fmaf(f1.x, f1.x, q2[0]); q2[1] = fmaf(f1.x, f1.y, q2[1]);
        q2[2] = fmaf(f1.x, f1.z, q2[2]); q2[3] = fmaf(f1.x, f1.w, q2[3]);
        q2[4] = fmaf(f1.y, f1.y, q2[4]); q2[5] = fmaf(f1.y, f1.z, q2[5]);
        q2[6] = fmaf(f1.y, f1.w, q2[6]); q2[7] = fmaf(f1.z, f1.z, q2[7]);
        q2[8] = fmaf(f1.z, f1.w, q2[8]); q2[9] = fmaf(f1.w, f1.w, q2[9]);
      }
    }

    // 7 pure-DPP reductions -> uniform (SGPR) wave totals. Zero DS ops.
    const float rx = wsum_bcast(sax);
    const float ry = wsum_bcast(say);
    const float rz = wsum_bcast(saz);
    const float vx = wsum_bcast(svx);
    const float vy = wsum_bcast(svy);
    const float vz = wsum_bcast(svz);
    const float vw = wsum_bcast(svw);

    const float nvf = (float)nv, inv = 1.f / nvf;
    const float cx = (float)coors[k * 4 + 3] * 0.2f + 0.1f;
    const float cy = (float)coors[k * 4 + 2] * 0.2f - 39.9f;
    const float o0 = -rx * inv, o1 = -ry * inv, o2 = -rz * inv;
    const float o3 = -cx, o4 = -cy;

    // lane-parallel cross-moment accumulation (1 register)
    {
      float add = 0.f;
      if (lane < 4) {
        add = (lane == 0) ? vx : (lane == 1) ? vy : (lane == 2) ? vz : vw;
      } else if (lane >= 14 && lane < 34) {
        const float sva = (sa == 0) ? vx : (sa == 1) ? vy : (sa == 2) ? vz : vw;
        const float ob = (sb == 0) ? o0 : (sb == 1) ? o1
                       : (sb == 2) ? o2 : (sb == 3) ? o3 : o4;
        add = sva * ob;
      } else if (lane >= 34 && lane < 39) {
        const int b = lane - 34;
        const float ob = (b == 0) ? o0 : (b == 1) ? o1
                       : (b == 2) ? o2 : (b == 3) ? o3 : o4;
        add = nvf * ob;
      } else if (lane >= 39 && lane < 54) {
        const float oa = (ub == 0) ? o0 : (ub == 1) ? o1
                       : (ub == 2) ? o2 : (ub == 3) ? o3 : o4;
        const float ob = (ub2 == 0) ? o0 : (ub2 == 1) ? o1
                       : (ub2 == 2) ? o2 : (ub2 == 3) ? o3 : o4;
        add = nvf * oa * ob;
      }
      oacc += add;
    }

    if (lane == 0) {
      float4 r0; r0.x = vx; r0.y = vy; r0.z = vz; r0.w = vw;
      float4 r1; r1.x = rx; r1.y = ry; r1.z = rz; r1.w = nvf;
      rec[2 * (size_t)k] = r0;
      rec[2 * (size_t)k + 1] = r1;
    }

    // channel-quad folded MAX extrema (verified R10 scheme)
    float4 m4 = {-3e38f, -3e38f, -3e38f, -3e38f};
    int p = 0;
    for (; p + 8 <= nv; p += 8) {
      const float4 fa = pts[wid][p + g];
      const float4 fb = pts[wid][p + 4 + g];
      m4.x = fmaxf(m4.x, fmaf(fa.x, wx.x, fmaf(fa.y, wy.x, fmaf(fa.z, wz.x, fa.w * w3.x))));
      m4.y = fmaxf(m4.y, fmaf(fa.x, wx.y, fmaf(fa.y, wy.y, fmaf(fa.z, wz.y, fa.w * w3.y))));
      m4.z = fmaxf(m4.z, fmaf(fa.x, wx.z, fmaf(fa.y, wy.z, fmaf(fa.z, wz.z, fa.w * w3.z))));
      m4.w = fmaxf(m4.w, fmaf(fa.x, wx.w, fmaf(fa.y, wy.w, fmaf(fa.z, wz.w, fa.w * w3.w))));
      m4.x = fmaxf(m4.x, fmaf(fb.x, wx.x, fmaf(fb.y, wy.x, fmaf(fb.z, wz.x, fb.w * w3.x))));
      m4.y = fmaxf(m4.y, fmaf(fb.x, wx.y, fmaf(fb.y, wy.y, fmaf(fb.z, wz.y, fb.w * w3.y))));
      m4.z = fmaxf(m4.z, fmaf(fb.x, wx.z, fmaf(fb.y, wy.z, fmaf(fb.z, wz.z, fb.w * w3.z))));
      m4.w = fmaxf(m4.w, fmaf(fb.x, wx.w, fmaf(fb.y, wy.w, fmaf(fb.z, wz.w, fb.w * w3.w))));
    }
    if (p < nv) {  // predicated tail octet
      const int i0 = p + g, i1 = p + 4 + g;
      const float4 fa = pts[wid][i0];
      const float4 fb = pts[wid][i1];
      if (i0 < nv) {
        m4.x = fmaxf(m4.x, fmaf(fa.x, wx.x, fmaf(fa.y, wy.x, fmaf(fa.z, wz.x, fa.w * w3.x))));
        m4.y = fmaxf(m4.y, fmaf(fa.x, wx.y, fmaf(fa.y, wy.y, fmaf(fa.z, wz.y, fa.w * w3.y))));
        m4.z = fmaxf(m4.z, fmaf(fa.x, wx.z, fmaf(fa.y, wy.z, fmaf(fa.z, wz.z, fa.w * w3.z))));
        m4.w = fmaxf(m4.w, fmaf(fa.x, wx.w, fmaf(fa.y, wy.w, fmaf(fa.z, wz.w, fa.w * w3.w))));
      }
      if (i1 < nv) {
        m4.x = fmaxf(m4.x, fmaf(fb.x, wx.x, fmaf(fb.y, wy.x, fmaf(fb.z, wz.x, fb.w * w3.x))));
        m4.y = fmaxf(m4.y, fmaf(fb.x, wx.y, fmaf(fb.y, wy.y, fmaf(fb.z, wz.y, fb.w * w3.y))));
        m4.z = fmaxf(m4.z, fmaf(fb.x, wx.z, fmaf(fb.y, wy.z, fmaf(fb.z, wz.z, fb.w * w3.z))));
        m4.w = fmaxf(m4.w, fmaf(fb.x, wx.w, fmaf(fb.y, wy.w, fmaf(fb.z, wz.w, fb.w * w3.w))));
      }
    }
    m4.x = fmaxf(m4.x, __shfl_xor(m4.x, 16, 64));
    m4.y = fmaxf(m4.y, __shfl_xor(m4.y, 16, 64));
    m4.z = fmaxf(m4.z, __shfl_xor(m4.z, 16, 64));
    m4.w = fmaxf(m4.w, __shfl_xor(m4.w, 16, 64));
    m4.x = fmaxf(m4.x, __shfl_xor(m4.x, 32, 64));
    m4.y = fmaxf(m4.y, __shfl_xor(m4.y, 32, 64));
    m4.z = fmaxf(m4.z, __shfl_xor(m4.z, 32, 64));
    m4.w = fmaxf(m4.w, __shfl_xor(m4.w, 32, 64));
    if (lane < 16) ext[(size_t)k * 16 + q] = m4;
  }

  // ---- block partials: rows 0..3,14..53 from oacc; 4..13 from q2 ----
  if (lane < 54 && (lane < 4 || lane >= 14)) red[wid][lane] = oacc;
#pragma unroll
  for (int i = 0; i < 10; ++i) q2[i] = wred63(q2[i]);
  if (lane == 63) {
#pragma unroll
    for (int i = 0; i < 10; ++i) red[wid][4 + i] = q2[i];
  }
  __syncthreads();
  const int t = threadIdx.x;
  if (t < 54) {
    p54[t * NBLK + blockIdx.x] =
        red[0][t] + red[1][t] + red[2][t] + red[3][t];
  }
}

// ---------------- K2: reduce + assemble + scale/shift (1024 thr) ---------
__global__ void __launch_bounds__(1024) pfn_finalize(
    const float* __restrict__ p54, const float* __restrict__ W,
    const float* __restrict__ gamma, const float* __restrict__ beta,
    float invN, float* __restrict__ ss) {
  __shared__ float msum[54];
  __shared__ float m54[54];
  const int t = threadIdx.x;
  const int r = t >> 4, j = t & 15;  // 16 readers per row, rows 0..63
  if (r < 54) {
    const int chunk = NBLK >> 4;  // 80
    const float* row = p54 + (size_t)r * NBLK + j * chunk;
    float a0 = 0, a1 = 0, a2 = 0, a3 = 0, a4 = 0, a5 = 0, a6 = 0, a7 = 0;
    int b = 0;
    for (; b + 8 <= chunk; b += 8) {
      a0 += row[b];     a1 += row[b + 1]; a2 += row[b + 2]; a3 += row[b + 3];
      a4 += row[b + 4]; a5 += row[b + 5]; a6 += row[b + 6]; a7 += row[b + 7];
    }
    for (; b < chunk; ++b) a0 += row[b];
    float s = ((a0 + a1) + (a2 + a3)) + ((a4 + a5) + (a6 + a7));
    s += __shfl_xor(s, 1, 64);  // combine the 16 readers (same wave,
    s += __shfl_xor(s, 2, 64);  // lanes r*16.. within 64-lane groups)
    s += __shfl_xor(s, 4, 64);
    s += __shfl_xor(s, 8, 64);
    if (j == 0) msum[r] = s;
  }
  __syncthreads();
  // msum: [0..3]=Q1 [4..13]=Q2 [14..33]=S [34..38]=U1 [39..53]=U2
  if (t < 54) {
    float v;
    if (t < 9) {
      const int g2 = (t < 4) ? t : (t < 7 ? t - 4 : t - 7);
      v = msum[g2];
      if (t >= 4) v += msum[34 + (t - 4)];
    } else {
      int r2 = t - 9, c = 0;
      while (r2 >= 9 - c) { r2 -= 9 - c; ++c; }
      const int c2 = c + r2;
      const int a = (c < 4) ? c : (c < 7 ? c - 4 : c - 7);
      const int b2 = (c2 < 4) ? c2 : (c2 < 7 ? c2 - 4 : c2 - 7);
      const int lo = a < b2 ? a : b2, hi = a < b2 ? b2 : a;
      v = msum[4 + lo * (9 - lo) / 2 + (hi - lo)];  // 4x4 tri offsets 0/4/7/9
      if (c2 >= 4) v += msum[14 + a * 5 + (c2 - 4)];
      if (c >= 4) v += msum[14 + b2 * 5 + (c - 4)];
      if (c >= 4 && c2 >= 4) {
        const int ua = c - 4, ub = c2 - 4;  // ua <= ub
        v += msum[39 + ua * 5 - ua * (ua - 1) / 2 + (ub - ua)];
      }
    }
    m54[t] = v;
  }
  __syncthreads();
  if (t < 64) {
    float wc[9];
#pragma unroll
    for (int c = 0; c < 9; ++c) wc[c] = W[c * 64 + t];
    float mu = 0.f;
#pragma unroll
    for (int c = 0; c < 9; ++c) mu += m54[c] * invN * wc[c];
    float ex2 = 0.f;
    int idx = 9;
#pragma unroll
    for (int c = 0; c < 9; ++c)
#pragma unroll
      for (int c2 = c; c2 < 9; ++c2) {
        float v = m54[idx] * invN * wc[c] * wc[c2];
        ex2 += (c == c2) ? v : 2.f * v;
        ++idx;
      }
    const float var = ex2 - mu * mu;
    const float scale = gamma[t] * rsqrtf(var + 1e-3f);
    ss[t] = scale;
    ss[64 + t] = beta[t] - mu * scale;
  }
}

// ---------------- K3: bias + un-fold + BN + relu ----------------
__global__ void __launch_bounds__(256) pfn_apply(
    const float4* __restrict__ ext, const float4* __restrict__ rec,
    const int* __restrict__ coors, const float* __restrict__ W,
    const float* __restrict__ ss, int K, int P, float4* __restrict__ out) {
  const int t = blockIdx.x * 256 + threadIdx.x;
  if (t >= K * 16) return;
  const int k = t >> 4, j = t & 15;

  const float4* Wq = (const float4*)W;  // [9][16]
  const float4 v4 = Wq[4 * 16 + j], v5 = Wq[5 * 16 + j];
  const float4 v6 = Wq[6 * 16 + j], v7 = Wq[7 * 16 + j];
  const float4 v8 = Wq[8 * 16 + j];

  const float4 e = ext[t];
  const float4 rb = rec[2 * (size_t)k + 1];
  const float nvf = rb.w, inv = 1.f / nvf;
  const float cx = (float)coors[k * 4 + 3] * 0.2f + 0.1f;
  const float cy = (float)coors[k * 4 + 2] * 0.2f - 39.9f;
  const float o0 = -rb.x * inv, o1 = -rb.y * inv, o2 = -rb.z * inv;
  float4 bias;
  bias.x = v4.x * o0 + v5.x * o1 + v6.x * o2 - v7.x * cx - v8.x * cy;
  bias.y = v4.y * o0 + v5.y * o1 + v6.y * o2 - v7.y * cx - v8.y * cy;
  bias.z = v4.z * o0 + v5.z * o1 + v6.z * o2 - v7.z * cx - v8.z * cy;
  bias.w = v4.w * o0 + v5.w * o1 + v6.w * o2 - v7.w * cx - v8.w * cy;

  const float4 sc = ((const float4*)ss)[j];
  const float4 sh = ((const float4*)(ss + 64))[j];
  const bool masked = nvf < (float)P;

  float4 o;
  {
    const float sgn = (sc.x >= 0.f) ? 1.f : -1.f;
    float ev = sgn * e.x + bias.x;
    if (masked) ev = (sc.x >= 0.f) ? fmaxf(ev, 0.f) : fminf(ev, 0.f);
    o.x = fmaxf(fmaf(sc.x, ev, sh.x), 0.f);
  }
  {
    const float sgn = (sc.y >= 0.f) ? 1.f : -1.f;
    float ev = sgn * e.y + bias.y;
    if (masked) ev = (sc.y >= 0.f) ? fmaxf(ev, 0.f) : fminf(ev, 0.f);
    o.y = fmaxf(fmaf(sc.y, ev, sh.y), 0.f);
  }
  {
    const float sgn = (sc.z >= 0.f) ? 1.f : -1.f;
    float ev = sgn * e.z + bias.z;
    if (masked) ev = (sc.z >= 0.f) ? fmaxf(ev, 0.f) : fminf(ev, 0.f);
    o.z = fmaxf(fmaf(sc.z, ev, sh.z), 0.f);
  }
  {
    const float sgn = (sc.w >= 0.f) ? 1.f : -1.f;
    float ev = sgn * e.w + bias.w;
    if (masked) ev = (sc.w >= 0.f) ? fmaxf(ev, 0.f) : fminf(ev, 0.f);
    o.w = fmaxf(fmaf(sc.w, ev, sh.w), 0.f);
  }
  out[t] = o;
}

extern "C" void kernel_launch(void* const* d_in, const int* in_sizes, int n_in,
                              void* d_out, int out_size, void* d_ws,
                              size_t ws_size, hipStream_t stream) {
  const float4* feat = (const float4*)d_in[0];
  const int* nvox = (const int*)d_in[1];
  const int* coors = (const int*)d_in[2];
  const float* W = (const float*)d_in[3];
  const float* gamma = (const float*)d_in[4];
  const float* beta = (const float*)d_in[5];

  const int K = in_sizes[1];
  const int P = in_sizes[0] / (K * 4);

  // ws layout (floats): ss[128] | ext[K*16 f4] | rec[K*2 f4] | p54[54*NBLK]
  float* ss = (float*)d_ws;
  float4* ext = (float4*)(ss + 128);
  float4* rec = ext + (size_t)K * 16;
  float* p54 = (float*)(rec + (size_t)K * 2);

  const int nwaves = NBLK * 4;
  const int cnt = (K + nwaves - 1) / nwaves;  // contiguous pillars per wave

  pfn_main<<<NBLK, 256, 0, stream>>>(feat, nvox, coors, K, P, cnt, W, gamma,
                                     p54, ext, rec);
  pfn_finalize<<<1, 1024, 0, stream>>>(p54, W, gamma, beta,
                                       1.0f / (float)((long long)K * P), ss);
  pfn_apply<<<(K * 16 + 255) / 256, 256, 0, stream>>>(ext, rec, coors, W, ss,
                                                      K, P, (float4*)d_out);
}